// Round 9
// baseline (482.188 us; speedup 1.0000x reference)
//
#include <hip/hip_runtime.h>
#include <math.h>

typedef _Float16 f16;
typedef f16 f16x4 __attribute__((ext_vector_type(4)));
typedef f16 f16x8 __attribute__((ext_vector_type(8)));
typedef float f32x4 __attribute__((ext_vector_type(4)));

namespace {

constexpr int kB  = 32;
constexpr int kL  = 1024;
constexpr int kH  = 512;
constexpr int kP  = 336;
constexpr int kNL = 3;
constexpr int kNS = 32;
constexpr int kM  = 16;   // chunks per row (L/64)

// async global->LDS, 16B per lane. LDS dest is wave-uniform base + lane*16.
__device__ __forceinline__ void llds16(const void* g, void* s) {
  __builtin_amdgcn_global_load_lds((const __attribute__((address_space(1))) void*)g,
                                   (__attribute__((address_space(3))) void*)s, 16, 0, 0);
}

__device__ __forceinline__ float gelu_tanh(float y0) {
  float x3 = y0 * y0 * y0;
  float a = 0.7978845608028654f * fmaf(0.044715f, x3, y0);
  float aa = fminf(a, 15.f);
  float ex = __expf(2.f * aa);
  float th = 1.f - 2.f / (ex + 1.f);
  return 0.5f * y0 * (1.f + th);
}

// DPP row_shr:DIST within 16-lane rows, zero-fill for lanes (lane&15) < DIST.
template <int DIST>
__device__ __forceinline__ float dpp_shr0(float x) {
  return __builtin_bit_cast(float,
      __builtin_amdgcn_update_dpp(0, __builtin_bit_cast(int, x),
                                  0x110 | DIST, 0xF, 0xF, true));
}

__device__ __forceinline__ void csq(float& r, float& i) {
  float nr = r * r - i * i;
  i = 2.f * r * i;
  r = nr;
}

template <int DIST, int NCT>
__device__ __forceinline__ void scan_level(f32x4 (&a)[NCT], float t0r, float t0i,
                                           float t1r, float t1i) {
#pragma unroll
  for (int ct = 0; ct < NCT; ct++) {
    float r0 = dpp_shr0<DIST>(a[ct][0]);
    float i0 = dpp_shr0<DIST>(a[ct][1]);
    float r1 = dpp_shr0<DIST>(a[ct][2]);
    float i1 = dpp_shr0<DIST>(a[ct][3]);
    a[ct][0] = fmaf(t0r, r0, fmaf(-t0i, i0, a[ct][0]));
    a[ct][1] = fmaf(t0r, i0, fmaf(t0i, r0, a[ct][1]));
    a[ct][2] = fmaf(t1r, r1, fmaf(-t1i, i1, a[ct][2]));
    a[ct][3] = fmaf(t1r, i1, fmaf(t1i, r1, a[ct][3]));
  }
}

// ---------------------------------------------------------------------------
// K_pre: per (layer,h) build chunked-scan operands.
// ---------------------------------------------------------------------------
__global__ __launch_bounds__(64) void prep_kernel(
    const float* __restrict__ log_dt, const float* __restrict__ A_re,
    const float* __restrict__ A_im, const float* __restrict__ C_re,
    const float* __restrict__ C_im, const float* __restrict__ Dskip,
    f16* __restrict__ Afrag_c, f16* __restrict__ Afrag_a,
    float* __restrict__ rT) {
  int lh = blockIdx.x;   // layer*H + h
  int tid = threadIdx.x; // 0..63
  __shared__ float pr[32][65], pi[32][65];
  __shared__ float cre_s[32], cim_s[32];
  __shared__ float kt[64];

  float dt = expf(log_dt[lh]);
  if (tid < 32) {
    int n = tid;
    int idx = lh * 32 + n;
    float ar = A_re[idx], ai = A_im[idx];
    float dr = dt * ar, di = dt * ai;
    float er = expf(dr), cd = cosf(di), sd = sinf(di);
    float rr = er * cd, ri = er * sd;
    float sh = sinf(0.5f * di);
    float mr = expm1f(dr) * cd - 2.f * sh * sh;
    float mi = ri;
    float inv = 1.f / (ar * ar + ai * ai);
    float qr = (mr * ar + mi * ai) * inv;
    float qi = (mi * ar - mr * ai) * inv;
    float cre = C_re[idx], cim = C_im[idx];
    cre_s[n] = 2.f * (cre * qr - cim * qi);
    cim_s[n] = 2.f * (cre * qi + cim * qr);
    float xr = 1.f, xi = 0.f;
    for (int k = 0; k < 65; k++) {
      pr[n][k] = xr;
      pi[n][k] = xi;
      float nxr = xr * rr - xi * ri;
      float nxi = xr * ri + xi * rr;
      xr = nxr;
      xi = nxi;
    }
    rT[idx * 2] = pr[n][64];
    rT[idx * 2 + 1] = pi[n][64];
  }
  __syncthreads();
  {
    int d = tid;
    float s = 0.f;
    for (int n = 0; n < 32; n++) s += cre_s[n] * pr[n][d] - cim_s[n] * pi[n][d];
    if (d == 0) s += Dskip[lh];
    kt[d] = s;
  }
  __syncthreads();
  // A_c fragments: [K_toep | W2]
  f16* ac = Afrag_c + (size_t)lh * 8192;
#pragma unroll
  for (int it = 0; it < 16; it++) {
    int ks = it >> 2, rt = it & 3;
    int t = rt * 16 + (tid & 15);
    int kbase = ks * 32 + (tid >> 4) * 8;
    f16x8 v;
#pragma unroll
    for (int j = 0; j < 8; j++) {
      int k = kbase + j;
      float val;
      if (k < 64) {
        val = (t >= k) ? kt[t - k] : 0.f;
      } else {
        int s2 = k - 64;
        int n = s2 >> 1;
        float prr = pr[n][t + 1], pii = pi[n][t + 1];
        val = ((s2 & 1) == 0) ? (cre_s[n] * prr - cim_s[n] * pii)
                              : -(cre_s[n] * pii + cim_s[n] * prr);
      }
      v[j] = (f16)val;
    }
    *(f16x8*)(ac + (size_t)(it * 64 + tid) * 8) = v;
  }
  // A_a fragments (V)
  f16* aa = Afrag_a + (size_t)lh * 4096;
#pragma unroll
  for (int it = 0; it < 8; it++) {
    int ks = it >> 2, rt = it & 3;
    int s2 = rt * 16 + (tid & 15);
    int n = s2 >> 1;
    int kbase = ks * 32 + (tid >> 4) * 8;
    f16x8 v;
#pragma unroll
    for (int j = 0; j < 8; j++) {
      int t = kbase + j;
      v[j] = (f16)(((s2 & 1) == 0) ? pr[n][63 - t] : pi[n][63 - t]);
    }
    *(f16x8*)(aa + (size_t)(it * 64 + tid) * 8) = v;
  }
}

// ---------------------------------------------------------------------------
// K1: fp32 -> fp16 convert (weights)
// ---------------------------------------------------------------------------
__global__ void f32_to_f16_kernel(const float* __restrict__ s, f16* __restrict__ d,
                                  int n) {
  int i = blockIdx.x * 256 + threadIdx.x;
  if (i < n) d[i] = (f16)s[i];
}

// ---------------------------------------------------------------------------
// K1b: Wo fp32 -> MFMA-A-fragment-ordered fp16.
// woF[layer][mt(64)][ks(16)][lane(64)][8] = Wo[mt*16+(lane&15)][ks*32+(lane>>4)*8+j]
// ---------------------------------------------------------------------------
__global__ __launch_bounds__(256) void wo_frag_kernel(const float* __restrict__ Wo,
                                                      f16* __restrict__ woF) {
  int layer = blockIdx.y, mt = blockIdx.x;
  int t = threadIdx.x;
  int lane = t & 63;
  const float* w = Wo + (size_t)layer * 2 * kH * kH;
  f16* dst = woF + ((size_t)layer * 64 + mt) * 8192;
  int row = mt * 16 + (lane & 15);
  int cbase = (lane >> 4) * 8;
#pragma unroll
  for (int it = 0; it < 4; it++) {
    int ks = it * 4 + (t >> 6);
    f16x8 v;
#pragma unroll
    for (int j = 0; j < 8; j++) v[j] = (f16)w[(size_t)row * kH + ks * 32 + cbase + j];
    *(f16x8*)(dst + (size_t)(ks * 64 + lane) * 8) = v;
  }
}

// ---------------------------------------------------------------------------
// K2: (B, L, E) fp32 -> (B, E, L) fp16 transpose (input)
// ---------------------------------------------------------------------------
__global__ __launch_bounds__(256) void transpose_kernel(const float* __restrict__ x,
                                                        f16* __restrict__ u) {
  __shared__ float tile[32][33];
  int b = blockIdx.z;
  int l0 = blockIdx.x * 32, e0 = blockIdx.y * 32;
  int tx = threadIdx.x, ty = threadIdx.y;  // (32, 8)
#pragma unroll
  for (int k = 0; k < 4; k++)
    tile[ty + 8 * k][tx] = x[((size_t)b * kL + (size_t)(l0 + ty + 8 * k)) * kH + e0 + tx];
  __syncthreads();
#pragma unroll
  for (int k = 0; k < 4; k++)
    u[((size_t)b * kH + (size_t)(e0 + ty + 8 * k)) * kL + l0 + tx] =
        (f16)tile[tx][ty + 8 * k];
}

// ---------------------------------------------------------------------------
// K_t16f: f16 (B,H,L) -> MFMA-B-fragment-ordered ytF.
// ytF[b][lt(64)][kc(16)][lane(64)][8] = y[b][h=kc*32+(lane>>4)*8+j][l=lt*16+(lane&15)]
// ---------------------------------------------------------------------------
__global__ __launch_bounds__(256) void t16f_kernel(const f16* __restrict__ y,
                                                   f16* __restrict__ ytF) {
  __shared__ f16 tile[64][72];
  int b = blockIdx.z;
  int h0 = blockIdx.y * 64, l0 = blockIdx.x * 64;
  int t = threadIdx.x;
  int row = t >> 3, lc = t & 7;  // 32 rows x 8 col-chunks
#pragma unroll
  for (int r2 = 0; r2 < 2; r2++) {
    int r = row + 32 * r2;
    *(f16x8*)&tile[r][lc * 8] =
        *(const f16x8*)(y + (size_t)(b * kH + h0 + r) * kL + l0 + lc * 8);
  }
  __syncthreads();
  int li = t >> 2, sc = t & 3;  // 64 l-rows x 4 h-chunks (x2 iter)
#pragma unroll
  for (int s2 = 0; s2 < 2; s2++) {
    int s = sc + 4 * s2;
    f16x8 v;
#pragma unroll
    for (int j = 0; j < 8; j++) v[j] = tile[s * 8 + j][li];
    // lt = l0/16 + li/16, kc = h0/32 + s2, lane = sc*16 + (li&15)
    size_t off = ((((size_t)b * 64 + (l0 >> 4) + (li >> 4)) * 16) + (h0 >> 5) + s2) * 512
                 + (size_t)(sc * 16 + (li & 15)) * 8;
    *(f16x8*)(ytF + off) = v;
  }
}

// ---------------------------------------------------------------------------
// K_wy v5 (R18): ct=2 split (32 cols/block, grid 16x512 = 8192 waves).
// R3 counters showed memory-latency-bound (MfmaUtil 4%, VALUBusy 32%, HBM 12%)
// with too few co-resident waves. Scan is per-column-independent so the split
// does NOT duplicate scan work; acc halves (~VGPR 80-90 -> 5-6 waves/SIMD),
// 2x schedulable units. afc/afa re-reads double but are L2 hits.
// ---------------------------------------------------------------------------
__global__ __launch_bounds__(64) void chunk_wy_kernel(
    const f16* __restrict__ u, const f16* __restrict__ Afrag_a,
    const f16* __restrict__ Afrag_c, const float* __restrict__ rT,
    f16* __restrict__ yout, int layer) {
  __shared__ __align__(16) f16 Sl[2][16][72];  // [ct][c][row(64)+pad]
  int h = blockIdx.y;
  int lane = threadIdx.x;
  int col0 = blockIdx.x * 32;
  const f16* aa = Afrag_a + (size_t)(layer * kH + h) * 4096;
  const f16* ac = Afrag_c + (size_t)(layer * kH + h) * 8192;
  int k8 = lane >> 4, cl = lane & 15;  // k8 == q (C-layout quad)

  // u fragment addresses (16B per lane), reused in Phase A and Phase D
  const f16* gu[2];
#pragma unroll
  for (int ct = 0; ct < 2; ct++) {
    int col = col0 + ct * 16 + cl;
    int b = col >> 4, c = col & 15;
    gu[ct] = u + (size_t)(b * kH + h) * kL + c * 64 + k8 * 8;
  }

  // ---- Phase A: w = V @ u (u fragments loop-local, not carried)
  f32x4 acc[4][2] = {};
#pragma unroll
  for (int ks = 0; ks < 2; ks++) {
    f16x8 af[4], ufl[2];
#pragma unroll
    for (int rt = 0; rt < 4; rt++)
      af[rt] = *(const f16x8*)(aa + (size_t)((ks * 4 + rt) * 64 + lane) * 8);
#pragma unroll
    for (int ct = 0; ct < 2; ct++)
      ufl[ct] = *(const f16x8*)(gu[ct] + ks * 32);
#pragma unroll
    for (int rt = 0; rt < 4; rt++)
#pragma unroll
      for (int ct = 0; ct < 2; ct++)
        acc[rt][ct] =
            __builtin_amdgcn_mfma_f32_16x16x32_f16(af[rt], ufl[ct], acc[rt][ct], 0, 0, 0);
  }

  // ---- Phase B: prefix scan across chunks (cl lanes), per rt — DPP scan
  int lhb = (layer * kH + h) * 32;
#pragma unroll
  for (int rt = 0; rt < 4; rt++) {
    int n0 = rt * 8 + k8 * 2;
    float t0r = rT[(lhb + n0) * 2], t0i = rT[(lhb + n0) * 2 + 1];
    float t1r = rT[(lhb + n0 + 1) * 2], t1i = rT[(lhb + n0 + 1) * 2 + 1];
    scan_level<1, 2>(acc[rt], t0r, t0i, t1r, t1i);
    csq(t0r, t0i); csq(t1r, t1i);
    scan_level<2, 2>(acc[rt], t0r, t0i, t1r, t1i);
    csq(t0r, t0i); csq(t1r, t1i);
    scan_level<4, 2>(acc[rt], t0r, t0i, t1r, t1i);
    csq(t0r, t0i); csq(t1r, t1i);
    scan_level<8, 2>(acc[rt], t0r, t0i, t1r, t1i);
  }

  // ---- Phase C: exclusive shift (DPP row_shr:1, zero-fill), write S to LDS
#pragma unroll
  for (int rt = 0; rt < 4; rt++)
#pragma unroll
    for (int ct = 0; ct < 2; ct++) {
      f16x4 v;
#pragma unroll
      for (int reg = 0; reg < 4; reg++) {
        v[reg] = (f16)dpp_shr0<1>(acc[rt][ct][reg]);
      }
      *(f16x4*)&Sl[ct][cl][rt * 16 + k8 * 4] = v;
    }
  // wave-local LDS write->read ordering (no barrier needed, single wave)
  asm volatile("s_waitcnt lgkmcnt(0)" ::: "memory");

  // ---- Phase D: y = [Ktoep | W2] @ [u; S] (u re-loaded, L2-warm)
  f32x4 accD[4][2] = {};
#pragma unroll
  for (int ks = 0; ks < 4; ks++) {
    f16x8 af[4], bf[2];
#pragma unroll
    for (int rt = 0; rt < 4; rt++)
      af[rt] = *(const f16x8*)(ac + (size_t)((ks * 4 + rt) * 64 + lane) * 8);
#pragma unroll
    for (int ct = 0; ct < 2; ct++) {
      if (ks < 2)
        bf[ct] = *(const f16x8*)(gu[ct] + ks * 32);
      else
        bf[ct] = *(const f16x8*)&Sl[ct][cl][(ks - 2) * 32 + k8 * 8];
    }
#pragma unroll
    for (int rt = 0; rt < 4; rt++)
#pragma unroll
      for (int ct = 0; ct < 2; ct++)
        accD[rt][ct] =
            __builtin_amdgcn_mfma_f32_16x16x32_f16(af[rt], bf[ct], accD[rt][ct], 0, 0, 0);
  }

  // ---- epilogue: GELU + coalesced store (B,H,L)
#pragma unroll
  for (int ct = 0; ct < 2; ct++) {
    int col = col0 + ct * 16 + cl;
    int b = col >> 4, c = col & 15;
    f16* yp = yout + (size_t)(b * kH + h) * kL + c * 64;
#pragma unroll
    for (int rt = 0; rt < 4; rt++) {
      f16x4 v;
#pragma unroll
      for (int reg = 0; reg < 4; reg++) v[reg] = (f16)gelu_tanh(accD[rt][ct][reg]);
      *(f16x4*)(yp + rt * 16 + k8 * 4) = v;
    }
  }
}

// ---------------------------------------------------------------------------
// K4: GLU GEMM v9 (R18). v8 body (B-prefetch, VGPR 92, 51.2us) re-gridded to
// 1-WAVE blocks: 32 h (2 lower + 2 upper GLU mt) x 64 l per wave — identical
// per-wave work and register footprint, but 8192 independent schedulable
// units instead of 2048 4-wave blocks (no LDS/barriers -> grouping bought
// nothing but coarse packing; Occupancy was 19%). L2 traffic provably
// unchanged (each wave issues its own loads either way).
// History: R3 A+B prefetch -> 132 VGPR cliff (87us). R5 launch_bounds(256,4)
// -> clamp to 64 VGPR + scratch spill (88us). NEVER add min-waves here.
// ---------------------------------------------------------------------------
__global__ __launch_bounds__(64) void glu_mfma_kernel(
    const f16* __restrict__ ytF,  // fragment-ordered y^T
    const f16* __restrict__ woF,  // fragment-ordered Wo, this layer
    const float* __restrict__ bo, // (2H,)
    f16* __restrict__ uout) {     // (B, H, L)
  int lane = threadIdx.x;
  int b = blockIdx.z, h0 = blockIdx.y * 32, l0 = blockIdx.x * 64;

  // B fragment base: l-tile (l0>>4)+nt, k-chunk kc
  const f16* gB[4];
#pragma unroll
  for (int nt = 0; nt < 4; ++nt)
    gB[nt] = ytF + ((size_t)(b * 64 + (l0 >> 4) + nt) * 16) * 512 +
             (size_t)lane * 8;

  // A fragment pointers: 4 m-subtiles (2 per GLU half)
  const f16* gA[4];
#pragma unroll
  for (int i = 0; i < 4; ++i) {
    int mt = (i < 2) ? ((h0 >> 4) + i) : (32 + (h0 >> 4) + (i - 2));
    gA[i] = woF + ((size_t)mt * 16 * 64 + lane) * 8;
  }

  f32x4 acc[4][4] = {};
  f16x8 bv[2][4];

#pragma unroll
  for (int nt = 0; nt < 4; ++nt) bv[0][nt] = *(const f16x8*)(gB[nt]);

#pragma unroll
  for (int kc = 0; kc < 16; ++kc) {
    int cur = kc & 1, nxt = cur ^ 1;  // static under full unroll
    if (kc < 15) {
#pragma unroll
      for (int nt = 0; nt < 4; ++nt)
        bv[nxt][nt] = *(const f16x8*)(gB[nt] + (size_t)(kc + 1) * 512);
    }
    f16x8 av[4];
#pragma unroll
    for (int i = 0; i < 4; ++i)
      av[i] = *(const f16x8*)(gA[i] + (size_t)kc * 512);
#pragma unroll
    for (int i = 0; i < 4; ++i)
#pragma unroll
      for (int nt = 0; nt < 4; ++nt)
        acc[i][nt] =
            __builtin_amdgcn_mfma_f32_16x16x32_f16(av[i], bv[cur][nt], acc[i][nt], 0, 0, 0);
  }

  int col = lane & 15, q = lane >> 4;
  f16* ub = uout + (size_t)b * kH * kL;
#pragma unroll
  for (int i = 0; i < 2; ++i) {
#pragma unroll
    for (int reg = 0; reg < 4; ++reg) {
      int h = h0 + i * 16 + q * 4 + reg;
      float b1 = bo[h], b2 = bo[h + kH];
#pragma unroll
      for (int nt = 0; nt < 4; ++nt) {
        float z1 = acc[i][nt][reg] + b1;
        float z2 = acc[i + 2][nt][reg] + b2;
        float sg = 1.f / (1.f + __expf(-z2));
        ub[(size_t)h * kL + l0 + nt * 16 + col] = (f16)(z1 * sg);
      }
    }
  }
}

// ---------------------------------------------------------------------------
// K5: final projection via MFMA f16 (unchanged).
// ---------------------------------------------------------------------------
__global__ __launch_bounds__(256) void final_mfma_kernel(
    const f16* __restrict__ x, const f16* __restrict__ wout,
    const float* __restrict__ bout, float* __restrict__ outp) {
  __shared__ __align__(16) f16 At[16][64][8];
  __shared__ __align__(16) f16 Bt[16][64][8];
  int tid = threadIdx.x;
  int lane = tid & 63, w = tid >> 6;
  int wm = w >> 1, wn = w & 1;
  int lr = lane & 15, lc = lane >> 4;
  int b = blockIdx.z, p0 = blockIdx.y * 128, h0 = blockIdx.x * 128;
  const f16* xb = x + (size_t)b * kH * kL;

  f32x4 acc[4][4] = {};

  const f16* gA[4];
  const f16* gB[4];
#pragma unroll
  for (int i = 0; i < 4; ++i) {
    int st = w * 4 + i, mt = st >> 1, ks = st & 1;
    int prow = p0 + mt * 16 + lr;
    if (prow > kP - 1) prow = kP - 1;
    gA[i] = wout + (size_t)prow * kL + ks * 32 + lc * 8;
    int hrow = h0 + mt * 16 + lr;
    gB[i] = xb + (size_t)hrow * kL + ks * 32 + lc * 8;
  }

  for (int k0 = 0; k0 < kL; k0 += 64) {
#pragma unroll
    for (int i = 0; i < 4; ++i) {
      int st = w * 4 + i;
      llds16(gA[i] + k0, &At[st][0][0]);
      llds16(gB[i] + k0, &Bt[st][0][0]);
    }
    __syncthreads();
#pragma unroll
    for (int ks = 0; ks < 2; ++ks) {
      f16x8 av[4], bv[4];
#pragma unroll
      for (int i = 0; i < 4; ++i)
        av[i] = *(const f16x8*)At[(wm * 4 + i) * 2 + ks][lane];
#pragma unroll
      for (int nt = 0; nt < 4; ++nt)
        bv[nt] = *(const f16x8*)Bt[(wn * 4 + nt) * 2 + ks][lane];
#pragma unroll
      for (int i = 0; i < 4; ++i)
#pragma unroll
        for (int nt = 0; nt < 4; ++nt)
          acc[i][nt] =
              __builtin_amdgcn_mfma_f32_16x16x32_f16(av[i], bv[nt], acc[i][nt], 0, 0, 0);
    }
    __syncthreads();
  }

  int col = lane & 15, q = lane >> 4;
  float* ob = outp + (size_t)b * kP * kH;
#pragma unroll
  for (int i = 0; i < 4; ++i) {
#pragma unroll
    for (int reg = 0; reg < 4; ++reg) {
      int p = p0 + wm * 64 + i * 16 + q * 4 + reg;
      if (p < kP) {
        float bv2 = bout[p];
#pragma unroll
        for (int nt = 0; nt < 4; ++nt)
          ob[(size_t)p * kH + h0 + wn * 64 + nt * 16 + col] = acc[i][nt][reg] + bv2;
      }
    }
  }
}

}  // namespace

extern "C" void kernel_launch(void* const* d_in, const int* in_sizes, int n_in,
                              void* d_out, int out_size, void* d_ws, size_t ws_size,
                              hipStream_t stream) {
  const float* x_enc  = (const float*)d_in[0];
  const float* log_dt = (const float*)d_in[4];
  const float* A_re   = (const float*)d_in[5];
  const float* A_im   = (const float*)d_in[6];
  const float* C_re   = (const float*)d_in[7];
  const float* C_im   = (const float*)d_in[8];
  const float* Dskip  = (const float*)d_in[9];
  const float* Wo     = (const float*)d_in[10];
  const float* bo     = (const float*)d_in[11];
  const float* W_out  = (const float*)d_in[12];
  const float* b_out  = (const float*)d_in[13];
  float* out = (float*)d_out;

  char* wsb = (char*)d_ws;
  f16* u16    = (f16*)(wsb);                   // 32 MB: u (B,H,L)
  f16* ybuf   = (f16*)(wsb + 33554432);        // 32 MB: y (B,H,L)
  f16* ytF    = (f16*)(wsb + 67108864);        // 32 MB: fragment-ordered y^T
  f16* woF    = (f16*)(wsb + 100663296);       // 3 MB fragment-ordered Wo
  f16* wout16 = (f16*)(wsb + 103809024);       // 672 KB
  f16* afc    = (f16*)(wsb + 104497152);       // 24 MB  [lh][16][64][8]
  f16* afa    = (f16*)(wsb + 129662976);       // 12 MB  [lh][8][64][8]
  float* rT   = (float*)(wsb + 142245888);     // 384 KB [lh][32][2]

  const int nwp = kP * kL;
  f32_to_f16_kernel<<<(nwp + 255) / 256, 256, 0, stream>>>(W_out, wout16, nwp);
  wo_frag_kernel<<<dim3(64, kNL), 256, 0, stream>>>(Wo, woF);

  prep_kernel<<<kNL * kH, 64, 0, stream>>>(log_dt, A_re, A_im, C_re, C_im, Dskip,
                                           afc, afa, rT);

  transpose_kernel<<<dim3(kL / 32, kH / 32, kB), dim3(32, 8), 0, stream>>>(x_enc, u16);

  for (int layer = 0; layer < kNL; layer++) {
    chunk_wy_kernel<<<dim3(16, kH), 64, 0, stream>>>(u16, afa, afc, rT, ybuf, layer);
    t16f_kernel<<<dim3(kL / 64, kH / 64, kB), 256, 0, stream>>>(ybuf, ytF);
    glu_mfma_kernel<<<dim3(kL / 64, kH / 32, kB), 64, 0, stream>>>(
        ytF, woF + (size_t)layer * 64 * 8192, bo + (size_t)layer * 2 * kH, u16);
  }

  final_mfma_kernel<<<dim3(kH / 128, 3, kB), 256, 0, stream>>>(u16, wout16, b_out, out);
}

// Round 10
// 476.712 us; speedup vs baseline: 1.0115x; 1.0115x over previous
//
#include <hip/hip_runtime.h>
#include <math.h>

typedef _Float16 f16;
typedef f16 f16x4 __attribute__((ext_vector_type(4)));
typedef f16 f16x8 __attribute__((ext_vector_type(8)));
typedef float f32x4 __attribute__((ext_vector_type(4)));

namespace {

constexpr int kB  = 32;
constexpr int kL  = 1024;
constexpr int kH  = 512;
constexpr int kP  = 336;
constexpr int kNL = 3;
constexpr int kNS = 32;
constexpr int kM  = 16;   // chunks per row (L/64)

// async global->LDS, 16B per lane. LDS dest is wave-uniform base + lane*16.
__device__ __forceinline__ void llds16(const void* g, void* s) {
  __builtin_amdgcn_global_load_lds((const __attribute__((address_space(1))) void*)g,
                                   (__attribute__((address_space(3))) void*)s, 16, 0, 0);
}

__device__ __forceinline__ float gelu_tanh(float y0) {
  float x3 = y0 * y0 * y0;
  float a = 0.7978845608028654f * fmaf(0.044715f, x3, y0);
  float aa = fminf(a, 15.f);
  float ex = __expf(2.f * aa);
  float th = 1.f - 2.f / (ex + 1.f);
  return 0.5f * y0 * (1.f + th);
}

// DPP row_shr:DIST within 16-lane rows, zero-fill for lanes (lane&15) < DIST.
template <int DIST>
__device__ __forceinline__ float dpp_shr0(float x) {
  return __builtin_bit_cast(float,
      __builtin_amdgcn_update_dpp(0, __builtin_bit_cast(int, x),
                                  0x110 | DIST, 0xF, 0xF, true));
}

__device__ __forceinline__ void csq(float& r, float& i) {
  float nr = r * r - i * i;
  i = 2.f * r * i;
  r = nr;
}

template <int DIST, int NCT>
__device__ __forceinline__ void scan_level(f32x4 (&a)[NCT], float t0r, float t0i,
                                           float t1r, float t1i) {
#pragma unroll
  for (int ct = 0; ct < NCT; ct++) {
    float r0 = dpp_shr0<DIST>(a[ct][0]);
    float i0 = dpp_shr0<DIST>(a[ct][1]);
    float r1 = dpp_shr0<DIST>(a[ct][2]);
    float i1 = dpp_shr0<DIST>(a[ct][3]);
    a[ct][0] = fmaf(t0r, r0, fmaf(-t0i, i0, a[ct][0]));
    a[ct][1] = fmaf(t0r, i0, fmaf(t0i, r0, a[ct][1]));
    a[ct][2] = fmaf(t1r, r1, fmaf(-t1i, i1, a[ct][2]));
    a[ct][3] = fmaf(t1r, i1, fmaf(t1i, r1, a[ct][3]));
  }
}

// ---------------------------------------------------------------------------
// K_pre: per (layer,h) build chunked-scan operands.
// ---------------------------------------------------------------------------
__global__ __launch_bounds__(64) void prep_kernel(
    const float* __restrict__ log_dt, const float* __restrict__ A_re,
    const float* __restrict__ A_im, const float* __restrict__ C_re,
    const float* __restrict__ C_im, const float* __restrict__ Dskip,
    f16* __restrict__ Afrag_c, f16* __restrict__ Afrag_a,
    float* __restrict__ rT) {
  int lh = blockIdx.x;   // layer*H + h
  int tid = threadIdx.x; // 0..63
  __shared__ float pr[32][65], pi[32][65];
  __shared__ float cre_s[32], cim_s[32];
  __shared__ float kt[64];

  float dt = expf(log_dt[lh]);
  if (tid < 32) {
    int n = tid;
    int idx = lh * 32 + n;
    float ar = A_re[idx], ai = A_im[idx];
    float dr = dt * ar, di = dt * ai;
    float er = expf(dr), cd = cosf(di), sd = sinf(di);
    float rr = er * cd, ri = er * sd;
    float sh = sinf(0.5f * di);
    float mr = expm1f(dr) * cd - 2.f * sh * sh;
    float mi = ri;
    float inv = 1.f / (ar * ar + ai * ai);
    float qr = (mr * ar + mi * ai) * inv;
    float qi = (mi * ar - mr * ai) * inv;
    float cre = C_re[idx], cim = C_im[idx];
    cre_s[n] = 2.f * (cre * qr - cim * qi);
    cim_s[n] = 2.f * (cre * qi + cim * qr);
    float xr = 1.f, xi = 0.f;
    for (int k = 0; k < 65; k++) {
      pr[n][k] = xr;
      pi[n][k] = xi;
      float nxr = xr * rr - xi * ri;
      float nxi = xr * ri + xi * rr;
      xr = nxr;
      xi = nxi;
    }
    rT[idx * 2] = pr[n][64];
    rT[idx * 2 + 1] = pi[n][64];
  }
  __syncthreads();
  {
    int d = tid;
    float s = 0.f;
    for (int n = 0; n < 32; n++) s += cre_s[n] * pr[n][d] - cim_s[n] * pi[n][d];
    if (d == 0) s += Dskip[lh];
    kt[d] = s;
  }
  __syncthreads();
  // A_c fragments: [K_toep | W2]
  f16* ac = Afrag_c + (size_t)lh * 8192;
#pragma unroll
  for (int it = 0; it < 16; it++) {
    int ks = it >> 2, rt = it & 3;
    int t = rt * 16 + (tid & 15);
    int kbase = ks * 32 + (tid >> 4) * 8;
    f16x8 v;
#pragma unroll
    for (int j = 0; j < 8; j++) {
      int k = kbase + j;
      float val;
      if (k < 64) {
        val = (t >= k) ? kt[t - k] : 0.f;
      } else {
        int s2 = k - 64;
        int n = s2 >> 1;
        float prr = pr[n][t + 1], pii = pi[n][t + 1];
        val = ((s2 & 1) == 0) ? (cre_s[n] * prr - cim_s[n] * pii)
                              : -(cre_s[n] * pii + cim_s[n] * prr);
      }
      v[j] = (f16)val;
    }
    *(f16x8*)(ac + (size_t)(it * 64 + tid) * 8) = v;
  }
  // A_a fragments (V)
  f16* aa = Afrag_a + (size_t)lh * 4096;
#pragma unroll
  for (int it = 0; it < 8; it++) {
    int ks = it >> 2, rt = it & 3;
    int s2 = rt * 16 + (tid & 15);
    int n = s2 >> 1;
    int kbase = ks * 32 + (tid >> 4) * 8;
    f16x8 v;
#pragma unroll
    for (int j = 0; j < 8; j++) {
      int t = kbase + j;
      v[j] = (f16)(((s2 & 1) == 0) ? pr[n][63 - t] : pi[n][63 - t]);
    }
    *(f16x8*)(aa + (size_t)(it * 64 + tid) * 8) = v;
  }
}

// ---------------------------------------------------------------------------
// K1: fp32 -> fp16 convert (weights)
// ---------------------------------------------------------------------------
__global__ void f32_to_f16_kernel(const float* __restrict__ s, f16* __restrict__ d,
                                  int n) {
  int i = blockIdx.x * 256 + threadIdx.x;
  if (i < n) d[i] = (f16)s[i];
}

// ---------------------------------------------------------------------------
// K1b: Wo fp32 -> MFMA-A-fragment-ordered fp16.
// woF[layer][mt(64)][ks(16)][lane(64)][8] = Wo[mt*16+(lane&15)][ks*32+(lane>>4)*8+j]
// ---------------------------------------------------------------------------
__global__ __launch_bounds__(256) void wo_frag_kernel(const float* __restrict__ Wo,
                                                      f16* __restrict__ woF) {
  int layer = blockIdx.y, mt = blockIdx.x;
  int t = threadIdx.x;
  int lane = t & 63;
  const float* w = Wo + (size_t)layer * 2 * kH * kH;
  f16* dst = woF + ((size_t)layer * 64 + mt) * 8192;
  int row = mt * 16 + (lane & 15);
  int cbase = (lane >> 4) * 8;
#pragma unroll
  for (int it = 0; it < 4; it++) {
    int ks = it * 4 + (t >> 6);
    f16x8 v;
#pragma unroll
    for (int j = 0; j < 8; j++) v[j] = (f16)w[(size_t)row * kH + ks * 32 + cbase + j];
    *(f16x8*)(dst + (size_t)(ks * 64 + lane) * 8) = v;
  }
}

// ---------------------------------------------------------------------------
// K2: (B, L, E) fp32 -> (B, E, L) fp16 transpose (input)
// ---------------------------------------------------------------------------
__global__ __launch_bounds__(256) void transpose_kernel(const float* __restrict__ x,
                                                        f16* __restrict__ u) {
  __shared__ float tile[32][33];
  int b = blockIdx.z;
  int l0 = blockIdx.x * 32, e0 = blockIdx.y * 32;
  int tx = threadIdx.x, ty = threadIdx.y;  // (32, 8)
#pragma unroll
  for (int k = 0; k < 4; k++)
    tile[ty + 8 * k][tx] = x[((size_t)b * kL + (size_t)(l0 + ty + 8 * k)) * kH + e0 + tx];
  __syncthreads();
#pragma unroll
  for (int k = 0; k < 4; k++)
    u[((size_t)b * kH + (size_t)(e0 + ty + 8 * k)) * kL + l0 + tx] =
        (f16)tile[tx][ty + 8 * k];
}

// ---------------------------------------------------------------------------
// K_t16f: f16 (B,H,L) -> MFMA-B-fragment-ordered ytF.
// ytF[b][lt(64)][kc(16)][lane(64)][8] = y[b][h=kc*32+(lane>>4)*8+j][l=lt*16+(lane&15)]
// ---------------------------------------------------------------------------
__global__ __launch_bounds__(256) void t16f_kernel(const f16* __restrict__ y,
                                                   f16* __restrict__ ytF) {
  __shared__ f16 tile[64][72];
  int b = blockIdx.z;
  int h0 = blockIdx.y * 64, l0 = blockIdx.x * 64;
  int t = threadIdx.x;
  int row = t >> 3, lc = t & 7;  // 32 rows x 8 col-chunks
#pragma unroll
  for (int r2 = 0; r2 < 2; r2++) {
    int r = row + 32 * r2;
    *(f16x8*)&tile[r][lc * 8] =
        *(const f16x8*)(y + (size_t)(b * kH + h0 + r) * kL + l0 + lc * 8);
  }
  __syncthreads();
  int li = t >> 2, sc = t & 3;  // 64 l-rows x 4 h-chunks (x2 iter)
#pragma unroll
  for (int s2 = 0; s2 < 2; s2++) {
    int s = sc + 4 * s2;
    f16x8 v;
#pragma unroll
    for (int j = 0; j < 8; j++) v[j] = tile[s * 8 + j][li];
    // lt = l0/16 + li/16, kc = h0/32 + s2, lane = sc*16 + (li&15)
    size_t off = ((((size_t)b * 64 + (l0 >> 4) + (li >> 4)) * 16) + (h0 >> 5) + s2) * 512
                 + (size_t)(sc * 16 + (li & 15)) * 8;
    *(f16x8*)(ytF + off) = v;
  }
}

// ---------------------------------------------------------------------------
// K_wy v5 (kept from R18 — measured win: ~9 us/launch saved vs ct=4).
// ct=2 split (32 cols/block, grid 16x512 = 8192 waves). Scan is per-column-
// independent so the split does NOT duplicate scan work; acc halves
// (VGPR ~80-90 -> 5-6 waves/SIMD), 2x schedulable units.
// ---------------------------------------------------------------------------
__global__ __launch_bounds__(64) void chunk_wy_kernel(
    const f16* __restrict__ u, const f16* __restrict__ Afrag_a,
    const f16* __restrict__ Afrag_c, const float* __restrict__ rT,
    f16* __restrict__ yout, int layer) {
  __shared__ __align__(16) f16 Sl[2][16][72];  // [ct][c][row(64)+pad]
  int h = blockIdx.y;
  int lane = threadIdx.x;
  int col0 = blockIdx.x * 32;
  const f16* aa = Afrag_a + (size_t)(layer * kH + h) * 4096;
  const f16* ac = Afrag_c + (size_t)(layer * kH + h) * 8192;
  int k8 = lane >> 4, cl = lane & 15;  // k8 == q (C-layout quad)

  // u fragment addresses (16B per lane), reused in Phase A and Phase D
  const f16* gu[2];
#pragma unroll
  for (int ct = 0; ct < 2; ct++) {
    int col = col0 + ct * 16 + cl;
    int b = col >> 4, c = col & 15;
    gu[ct] = u + (size_t)(b * kH + h) * kL + c * 64 + k8 * 8;
  }

  // ---- Phase A: w = V @ u (u fragments loop-local, not carried)
  f32x4 acc[4][2] = {};
#pragma unroll
  for (int ks = 0; ks < 2; ks++) {
    f16x8 af[4], ufl[2];
#pragma unroll
    for (int rt = 0; rt < 4; rt++)
      af[rt] = *(const f16x8*)(aa + (size_t)((ks * 4 + rt) * 64 + lane) * 8);
#pragma unroll
    for (int ct = 0; ct < 2; ct++)
      ufl[ct] = *(const f16x8*)(gu[ct] + ks * 32);
#pragma unroll
    for (int rt = 0; rt < 4; rt++)
#pragma unroll
      for (int ct = 0; ct < 2; ct++)
        acc[rt][ct] =
            __builtin_amdgcn_mfma_f32_16x16x32_f16(af[rt], ufl[ct], acc[rt][ct], 0, 0, 0);
  }

  // ---- Phase B: prefix scan across chunks (cl lanes), per rt — DPP scan
  int lhb = (layer * kH + h) * 32;
#pragma unroll
  for (int rt = 0; rt < 4; rt++) {
    int n0 = rt * 8 + k8 * 2;
    float t0r = rT[(lhb + n0) * 2], t0i = rT[(lhb + n0) * 2 + 1];
    float t1r = rT[(lhb + n0 + 1) * 2], t1i = rT[(lhb + n0 + 1) * 2 + 1];
    scan_level<1, 2>(acc[rt], t0r, t0i, t1r, t1i);
    csq(t0r, t0i); csq(t1r, t1i);
    scan_level<2, 2>(acc[rt], t0r, t0i, t1r, t1i);
    csq(t0r, t0i); csq(t1r, t1i);
    scan_level<4, 2>(acc[rt], t0r, t0i, t1r, t1i);
    csq(t0r, t0i); csq(t1r, t1i);
    scan_level<8, 2>(acc[rt], t0r, t0i, t1r, t1i);
  }

  // ---- Phase C: exclusive shift (DPP row_shr:1, zero-fill), write S to LDS
#pragma unroll
  for (int rt = 0; rt < 4; rt++)
#pragma unroll
    for (int ct = 0; ct < 2; ct++) {
      f16x4 v;
#pragma unroll
      for (int reg = 0; reg < 4; reg++) {
        v[reg] = (f16)dpp_shr0<1>(acc[rt][ct][reg]);
      }
      *(f16x4*)&Sl[ct][cl][rt * 16 + k8 * 4] = v;
    }
  // wave-local LDS write->read ordering (no barrier needed, single wave)
  asm volatile("s_waitcnt lgkmcnt(0)" ::: "memory");

  // ---- Phase D: y = [Ktoep | W2] @ [u; S] (u re-loaded, L2-warm)
  f32x4 accD[4][2] = {};
#pragma unroll
  for (int ks = 0; ks < 4; ks++) {
    f16x8 af[4], bf[2];
#pragma unroll
    for (int rt = 0; rt < 4; rt++)
      af[rt] = *(const f16x8*)(ac + (size_t)((ks * 4 + rt) * 64 + lane) * 8);
#pragma unroll
    for (int ct = 0; ct < 2; ct++) {
      if (ks < 2)
        bf[ct] = *(const f16x8*)(gu[ct] + ks * 32);
      else
        bf[ct] = *(const f16x8*)&Sl[ct][cl][(ks - 2) * 32 + k8 * 8];
    }
#pragma unroll
    for (int rt = 0; rt < 4; rt++)
#pragma unroll
      for (int ct = 0; ct < 2; ct++)
        accD[rt][ct] =
            __builtin_amdgcn_mfma_f32_16x16x32_f16(af[rt], bf[ct], accD[rt][ct], 0, 0, 0);
  }

  // ---- epilogue: GELU + coalesced store (B,H,L)
#pragma unroll
  for (int ct = 0; ct < 2; ct++) {
    int col = col0 + ct * 16 + cl;
    int b = col >> 4, c = col & 15;
    f16* yp = yout + (size_t)(b * kH + h) * kL + c * 64;
#pragma unroll
    for (int rt = 0; rt < 4; rt++) {
      f16x4 v;
#pragma unroll
      for (int reg = 0; reg < 4; reg++) v[reg] = (f16)gelu_tanh(accD[rt][ct][reg]);
      *(f16x4*)(yp + rt * 16 + k8 * 4) = v;
    }
  }
}

// ---------------------------------------------------------------------------
// K4: GLU GEMM v8 (REVERTED to R6-measured form: 51.2us, VGPR 92, 4-wave
// blocks). R8's 1-wave re-grid regressed to 64us at IDENTICAL VGPR/occupancy:
// the per-CU workgroup-slot limit (not VGPR) caps resident waves for tiny
// blocks, and 4x more dispatches + loss of the block's correlated woF L2
// accesses cost ~25%. LESSON: keep >=4 waves/block for this kernel.
// History: R3 A+B prefetch -> 132 VGPR cliff (87us). R5 launch_bounds(256,4)
// -> clamp to 64 VGPR + scratch spill (88us). NEVER add min-waves here.
// ---------------------------------------------------------------------------
__global__ __launch_bounds__(256) void glu_mfma_kernel(
    const f16* __restrict__ ytF,  // fragment-ordered y^T
    const f16* __restrict__ woF,  // fragment-ordered Wo, this layer
    const float* __restrict__ bo, // (2H,)
    f16* __restrict__ uout) {     // (B, H, L)
  int tid = threadIdx.x;
  int lane = tid & 63, w = tid >> 6;
  int wm = w >> 1, wn = w & 1;
  int b = blockIdx.z, h0 = blockIdx.y * 64, l0 = blockIdx.x * 128;

  // B fragment base: l-tile (l0>>4)+wn*4+nt, k-chunk kc
  const f16* gB[4];
#pragma unroll
  for (int nt = 0; nt < 4; ++nt)
    gB[nt] = ytF + ((size_t)(b * 64 + (l0 >> 4) + wn * 4 + nt) * 16) * 512 +
             (size_t)lane * 8;

  // A fragment pointers: 4 m-subtiles for this wave (2 per GLU half)
  const f16* gA[4];
#pragma unroll
  for (int i = 0; i < 4; ++i) {
    int mt = (i < 2) ? ((h0 >> 4) + wm * 2 + i) : (32 + (h0 >> 4) + wm * 2 + (i - 2));
    gA[i] = woF + ((size_t)mt * 16 * 64 + lane) * 8;
  }

  f32x4 acc[4][4] = {};
  f16x8 bv[2][4];

#pragma unroll
  for (int nt = 0; nt < 4; ++nt) bv[0][nt] = *(const f16x8*)(gB[nt]);

#pragma unroll
  for (int kc = 0; kc < 16; ++kc) {
    int cur = kc & 1, nxt = cur ^ 1;  // static under full unroll
    if (kc < 15) {
#pragma unroll
      for (int nt = 0; nt < 4; ++nt)
        bv[nxt][nt] = *(const f16x8*)(gB[nt] + (size_t)(kc + 1) * 512);
    }
    f16x8 av[4];
#pragma unroll
    for (int i = 0; i < 4; ++i)
      av[i] = *(const f16x8*)(gA[i] + (size_t)kc * 512);
#pragma unroll
    for (int i = 0; i < 4; ++i)
#pragma unroll
      for (int nt = 0; nt < 4; ++nt)
        acc[i][nt] =
            __builtin_amdgcn_mfma_f32_16x16x32_f16(av[i], bv[cur][nt], acc[i][nt], 0, 0, 0);
  }

  int col = lane & 15, q = lane >> 4;
  f16* ub = uout + (size_t)b * kH * kL;
#pragma unroll
  for (int i = 0; i < 2; ++i) {
#pragma unroll
    for (int reg = 0; reg < 4; ++reg) {
      int h = h0 + wm * 32 + i * 16 + q * 4 + reg;
      float b1 = bo[h], b2 = bo[h + kH];
#pragma unroll
      for (int nt = 0; nt < 4; ++nt) {
        float z1 = acc[i][nt][reg] + b1;
        float z2 = acc[i + 2][nt][reg] + b2;
        float sg = 1.f / (1.f + __expf(-z2));
        ub[(size_t)h * kL + l0 + wn * 64 + nt * 16 + col] = (f16)(z1 * sg);
      }
    }
  }
}

// ---------------------------------------------------------------------------
// K5: final projection via MFMA f16 (unchanged).
// ---------------------------------------------------------------------------
__global__ __launch_bounds__(256) void final_mfma_kernel(
    const f16* __restrict__ x, const f16* __restrict__ wout,
    const float* __restrict__ bout, float* __restrict__ outp) {
  __shared__ __align__(16) f16 At[16][64][8];
  __shared__ __align__(16) f16 Bt[16][64][8];
  int tid = threadIdx.x;
  int lane = tid & 63, w = tid >> 6;
  int wm = w >> 1, wn = w & 1;
  int lr = lane & 15, lc = lane >> 4;
  int b = blockIdx.z, p0 = blockIdx.y * 128, h0 = blockIdx.x * 128;
  const f16* xb = x + (size_t)b * kH * kL;

  f32x4 acc[4][4] = {};

  const f16* gA[4];
  const f16* gB[4];
#pragma unroll
  for (int i = 0; i < 4; ++i) {
    int st = w * 4 + i, mt = st >> 1, ks = st & 1;
    int prow = p0 + mt * 16 + lr;
    if (prow > kP - 1) prow = kP - 1;
    gA[i] = wout + (size_t)prow * kL + ks * 32 + lc * 8;
    int hrow = h0 + mt * 16 + lr;
    gB[i] = xb + (size_t)hrow * kL + ks * 32 + lc * 8;
  }

  for (int k0 = 0; k0 < kL; k0 += 64) {
#pragma unroll
    for (int i = 0; i < 4; ++i) {
      int st = w * 4 + i;
      llds16(gA[i] + k0, &At[st][0][0]);
      llds16(gB[i] + k0, &Bt[st][0][0]);
    }
    __syncthreads();
#pragma unroll
    for (int ks = 0; ks < 2; ++ks) {
      f16x8 av[4], bv[4];
#pragma unroll
      for (int i = 0; i < 4; ++i)
        av[i] = *(const f16x8*)At[(wm * 4 + i) * 2 + ks][lane];
#pragma unroll
      for (int nt = 0; nt < 4; ++nt)
        bv[nt] = *(const f16x8*)Bt[(wn * 4 + nt) * 2 + ks][lane];
#pragma unroll
      for (int i = 0; i < 4; ++i)
#pragma unroll
        for (int nt = 0; nt < 4; ++nt)
          acc[i][nt] =
              __builtin_amdgcn_mfma_f32_16x16x32_f16(av[i], bv[nt], acc[i][nt], 0, 0, 0);
    }
    __syncthreads();
  }

  int col = lane & 15, q = lane >> 4;
  float* ob = outp + (size_t)b * kP * kH;
#pragma unroll
  for (int i = 0; i < 4; ++i) {
#pragma unroll
    for (int reg = 0; reg < 4; ++reg) {
      int p = p0 + wm * 64 + i * 16 + q * 4 + reg;
      if (p < kP) {
        float bv2 = bout[p];
#pragma unroll
        for (int nt = 0; nt < 4; ++nt)
          ob[(size_t)p * kH + h0 + wn * 64 + nt * 16 + col] = acc[i][nt][reg] + bv2;
      }
    }
  }
}

}  // namespace

extern "C" void kernel_launch(void* const* d_in, const int* in_sizes, int n_in,
                              void* d_out, int out_size, void* d_ws, size_t ws_size,
                              hipStream_t stream) {
  const float* x_enc  = (const float*)d_in[0];
  const float* log_dt = (const float*)d_in[4];
  const float* A_re   = (const float*)d_in[5];
  const float* A_im   = (const float*)d_in[6];
  const float* C_re   = (const float*)d_in[7];
  const float* C_im   = (const float*)d_in[8];
  const float* Dskip  = (const float*)d_in[9];
  const float* Wo     = (const float*)d_in[10];
  const float* bo     = (const float*)d_in[11];
  const float* W_out  = (const float*)d_in[12];
  const float* b_out  = (const float*)d_in[13];
  float* out = (float*)d_out;

  char* wsb = (char*)d_ws;
  f16* u16    = (f16*)(wsb);                   // 32 MB: u (B,H,L)
  f16* ybuf   = (f16*)(wsb + 33554432);        // 32 MB: y (B,H,L)
  f16* ytF    = (f16*)(wsb + 67108864);        // 32 MB: fragment-ordered y^T
  f16* woF    = (f16*)(wsb + 100663296);       // 3 MB fragment-ordered Wo
  f16* wout16 = (f16*)(wsb + 103809024);       // 672 KB
  f16* afc    = (f16*)(wsb + 104497152);       // 24 MB  [lh][16][64][8]
  f16* afa    = (f16*)(wsb + 129662976);       // 12 MB  [lh][8][64][8]
  float* rT   = (float*)(wsb + 142245888);     // 384 KB [lh][32][2]

  const int nwp = kP * kL;
  f32_to_f16_kernel<<<(nwp + 255) / 256, 256, 0, stream>>>(W_out, wout16, nwp);
  wo_frag_kernel<<<dim3(64, kNL), 256, 0, stream>>>(Wo, woF);

  prep_kernel<<<kNL * kH, 64, 0, stream>>>(log_dt, A_re, A_im, C_re, C_im, Dskip,
                                           afc, afa, rT);

  transpose_kernel<<<dim3(kL / 32, kH / 32, kB), dim3(32, 8), 0, stream>>>(x_enc, u16);

  for (int layer = 0; layer < kNL; layer++) {
    chunk_wy_kernel<<<dim3(16, kH), 64, 0, stream>>>(u16, afa, afc, rT, ybuf, layer);
    t16f_kernel<<<dim3(kL / 64, kH / 64, kB), 256, 0, stream>>>(ybuf, ytF);
    glu_mfma_kernel<<<dim3(kL / 128, kH / 64, kB), 256, 0, stream>>>(
        ytF, woF + (size_t)layer * 64 * 8192, bo + (size_t)layer * 2 * kH, u16);
  }

  final_mfma_kernel<<<dim3(kH / 128, 3, kB), 256, 0, stream>>>(u16, wout16, b_out, out);
}

// Round 11
// 439.946 us; speedup vs baseline: 1.0960x; 1.0836x over previous
//
#include <hip/hip_runtime.h>
#include <math.h>

typedef _Float16 f16;
typedef f16 f16x4 __attribute__((ext_vector_type(4)));
typedef f16 f16x8 __attribute__((ext_vector_type(8)));
typedef float f32x4 __attribute__((ext_vector_type(4)));

namespace {

constexpr int kB  = 32;
constexpr int kL  = 1024;
constexpr int kH  = 512;
constexpr int kP  = 336;
constexpr int kNL = 3;
constexpr int kNS = 32;
constexpr int kM  = 16;   // chunks per row (L/64)

// async global->LDS, 16B per lane. LDS dest is wave-uniform base + lane*16.
__device__ __forceinline__ void llds16(const void* g, void* s) {
  __builtin_amdgcn_global_load_lds((const __attribute__((address_space(1))) void*)g,
                                   (__attribute__((address_space(3))) void*)s, 16, 0, 0);
}

__device__ __forceinline__ float gelu_tanh(float y0) {
  float x3 = y0 * y0 * y0;
  float a = 0.7978845608028654f * fmaf(0.044715f, x3, y0);
  float aa = fminf(a, 15.f);
  float ex = __expf(2.f * aa);
  float th = 1.f - 2.f / (ex + 1.f);
  return 0.5f * y0 * (1.f + th);
}

// DPP row_shr:DIST within 16-lane rows, zero-fill for lanes (lane&15) < DIST.
template <int DIST>
__device__ __forceinline__ float dpp_shr0(float x) {
  return __builtin_bit_cast(float,
      __builtin_amdgcn_update_dpp(0, __builtin_bit_cast(int, x),
                                  0x110 | DIST, 0xF, 0xF, true));
}

__device__ __forceinline__ void csq(float& r, float& i) {
  float nr = r * r - i * i;
  i = 2.f * r * i;
  r = nr;
}

template <int DIST, int NCT>
__device__ __forceinline__ void scan_level(f32x4 (&a)[NCT], float t0r, float t0i,
                                           float t1r, float t1i) {
#pragma unroll
  for (int ct = 0; ct < NCT; ct++) {
    float r0 = dpp_shr0<DIST>(a[ct][0]);
    float i0 = dpp_shr0<DIST>(a[ct][1]);
    float r1 = dpp_shr0<DIST>(a[ct][2]);
    float i1 = dpp_shr0<DIST>(a[ct][3]);
    a[ct][0] = fmaf(t0r, r0, fmaf(-t0i, i0, a[ct][0]));
    a[ct][1] = fmaf(t0r, i0, fmaf(t0i, r0, a[ct][1]));
    a[ct][2] = fmaf(t1r, r1, fmaf(-t1i, i1, a[ct][2]));
    a[ct][3] = fmaf(t1r, i1, fmaf(t1i, r1, a[ct][3]));
  }
}

// ---------------------------------------------------------------------------
// K_pre: per (layer,h) build chunked-scan operands.
// ---------------------------------------------------------------------------
__global__ __launch_bounds__(64) void prep_kernel(
    const float* __restrict__ log_dt, const float* __restrict__ A_re,
    const float* __restrict__ A_im, const float* __restrict__ C_re,
    const float* __restrict__ C_im, const float* __restrict__ Dskip,
    f16* __restrict__ Afrag_c, f16* __restrict__ Afrag_a,
    float* __restrict__ rT) {
  int lh = blockIdx.x;   // layer*H + h
  int tid = threadIdx.x; // 0..63
  __shared__ float pr[32][65], pi[32][65];
  __shared__ float cre_s[32], cim_s[32];
  __shared__ float kt[64];

  float dt = expf(log_dt[lh]);
  if (tid < 32) {
    int n = tid;
    int idx = lh * 32 + n;
    float ar = A_re[idx], ai = A_im[idx];
    float dr = dt * ar, di = dt * ai;
    float er = expf(dr), cd = cosf(di), sd = sinf(di);
    float rr = er * cd, ri = er * sd;
    float sh = sinf(0.5f * di);
    float mr = expm1f(dr) * cd - 2.f * sh * sh;
    float mi = ri;
    float inv = 1.f / (ar * ar + ai * ai);
    float qr = (mr * ar + mi * ai) * inv;
    float qi = (mi * ar - mr * ai) * inv;
    float cre = C_re[idx], cim = C_im[idx];
    cre_s[n] = 2.f * (cre * qr - cim * qi);
    cim_s[n] = 2.f * (cre * qi + cim * qr);
    float xr = 1.f, xi = 0.f;
    for (int k = 0; k < 65; k++) {
      pr[n][k] = xr;
      pi[n][k] = xi;
      float nxr = xr * rr - xi * ri;
      float nxi = xr * ri + xi * rr;
      xr = nxr;
      xi = nxi;
    }
    rT[idx * 2] = pr[n][64];
    rT[idx * 2 + 1] = pi[n][64];
  }
  __syncthreads();
  {
    int d = tid;
    float s = 0.f;
    for (int n = 0; n < 32; n++) s += cre_s[n] * pr[n][d] - cim_s[n] * pi[n][d];
    if (d == 0) s += Dskip[lh];
    kt[d] = s;
  }
  __syncthreads();
  // A_c fragments: [K_toep | W2]
  f16* ac = Afrag_c + (size_t)lh * 8192;
#pragma unroll
  for (int it = 0; it < 16; it++) {
    int ks = it >> 2, rt = it & 3;
    int t = rt * 16 + (tid & 15);
    int kbase = ks * 32 + (tid >> 4) * 8;
    f16x8 v;
#pragma unroll
    for (int j = 0; j < 8; j++) {
      int k = kbase + j;
      float val;
      if (k < 64) {
        val = (t >= k) ? kt[t - k] : 0.f;
      } else {
        int s2 = k - 64;
        int n = s2 >> 1;
        float prr = pr[n][t + 1], pii = pi[n][t + 1];
        val = ((s2 & 1) == 0) ? (cre_s[n] * prr - cim_s[n] * pii)
                              : -(cre_s[n] * pii + cim_s[n] * prr);
      }
      v[j] = (f16)val;
    }
    *(f16x8*)(ac + (size_t)(it * 64 + tid) * 8) = v;
  }
  // A_a fragments (V)
  f16* aa = Afrag_a + (size_t)lh * 4096;
#pragma unroll
  for (int it = 0; it < 8; it++) {
    int ks = it >> 2, rt = it & 3;
    int s2 = rt * 16 + (tid & 15);
    int n = s2 >> 1;
    int kbase = ks * 32 + (tid >> 4) * 8;
    f16x8 v;
#pragma unroll
    for (int j = 0; j < 8; j++) {
      int t = kbase + j;
      v[j] = (f16)(((s2 & 1) == 0) ? pr[n][63 - t] : pi[n][63 - t]);
    }
    *(f16x8*)(aa + (size_t)(it * 64 + tid) * 8) = v;
  }
}

// ---------------------------------------------------------------------------
// K1: fp32 -> fp16 convert (weights)
// ---------------------------------------------------------------------------
__global__ void f32_to_f16_kernel(const float* __restrict__ s, f16* __restrict__ d,
                                  int n) {
  int i = blockIdx.x * 256 + threadIdx.x;
  if (i < n) d[i] = (f16)s[i];
}

// ---------------------------------------------------------------------------
// K1b: Wo fp32 -> MFMA-A-fragment-ordered fp16.
// woF[layer][mt(64)][ks(16)][lane(64)][8] = Wo[mt*16+(lane&15)][ks*32+(lane>>4)*8+j]
// ---------------------------------------------------------------------------
__global__ __launch_bounds__(256) void wo_frag_kernel(const float* __restrict__ Wo,
                                                      f16* __restrict__ woF) {
  int layer = blockIdx.y, mt = blockIdx.x;
  int t = threadIdx.x;
  int lane = t & 63;
  const float* w = Wo + (size_t)layer * 2 * kH * kH;
  f16* dst = woF + ((size_t)layer * 64 + mt) * 8192;
  int row = mt * 16 + (lane & 15);
  int cbase = (lane >> 4) * 8;
#pragma unroll
  for (int it = 0; it < 4; it++) {
    int ks = it * 4 + (t >> 6);
    f16x8 v;
#pragma unroll
    for (int j = 0; j < 8; j++) v[j] = (f16)w[(size_t)row * kH + ks * 32 + cbase + j];
    *(f16x8*)(dst + (size_t)(ks * 64 + lane) * 8) = v;
  }
}

// ---------------------------------------------------------------------------
// K2: (B, L, E) fp32 -> (B, E, L) fp16 transpose (input)
// ---------------------------------------------------------------------------
__global__ __launch_bounds__(256) void transpose_kernel(const float* __restrict__ x,
                                                        f16* __restrict__ u) {
  __shared__ float tile[32][33];
  int b = blockIdx.z;
  int l0 = blockIdx.x * 32, e0 = blockIdx.y * 32;
  int tx = threadIdx.x, ty = threadIdx.y;  // (32, 8)
#pragma unroll
  for (int k = 0; k < 4; k++)
    tile[ty + 8 * k][tx] = x[((size_t)b * kL + (size_t)(l0 + ty + 8 * k)) * kH + e0 + tx];
  __syncthreads();
#pragma unroll
  for (int k = 0; k < 4; k++)
    u[((size_t)b * kH + (size_t)(e0 + ty + 8 * k)) * kL + l0 + tx] =
        (f16)tile[tx][ty + 8 * k];
}

// ---------------------------------------------------------------------------
// K_wyt (R20): chunk_wy FUSED with the t16f fragment-reorder — t16f deleted.
// t16f was a pure 64MB/layer global round-trip permuting y into ytF; chunk_wy
// already holds y in registers at its epilogue. A ytF word needs 8 consecutive
// h, so blocks = 8 waves = one aligned h-octet (kc=h>>5, hi=(h>>3)&3 constant
// within the octet; j = h&7 = wave id). Waves run the proven ct=2 pipeline
// independently, write GELU'd y to a padded LDS tile [colIdx][t|pad][j]
// (j contiguous -> gather is one ds_read_b128 per word), one barrier, then
// 512 threads store fully-formed 16B words (256B contiguous per 16 threads).
// ytF index algebra verified against t16f: ytF[b][lt=l>>4][kc][hi*16+(l&15)][j]
// with l = c*64 + rt*16 + pos.
// LDS: 8xSl 36.9KB + Yt 33.3KB = ~70KB -> 2 blocks/CU (matches VGPR<=128 tier).
// ---------------------------------------------------------------------------
__global__ __launch_bounds__(512) void chunk_wyt_kernel(
    const f16* __restrict__ u, const f16* __restrict__ Afrag_a,
    const f16* __restrict__ Afrag_c, const float* __restrict__ rT,
    f16* __restrict__ ytF, int layer) {
  __shared__ __align__(16) f16 Sl[8][2][16][72];  // per-wave scan buffer
  __shared__ __align__(16) f16 Yt[32][65][8];     // [colIdx][t (64, pad 65)][j]
  int tid = threadIdx.x;
  int w = tid >> 6, lane = tid & 63;
  int h = blockIdx.y * 8 + w;  // aligned octet: kc, hi uniform over block
  int col0 = blockIdx.x * 32;
  const f16* aa = Afrag_a + (size_t)(layer * kH + h) * 4096;
  const f16* ac = Afrag_c + (size_t)(layer * kH + h) * 8192;
  int k8 = lane >> 4, cl = lane & 15;

  // u fragment addresses (16B per lane), reused in Phase A and Phase D
  const f16* gu[2];
#pragma unroll
  for (int ct = 0; ct < 2; ct++) {
    int col = col0 + ct * 16 + cl;
    int b = col >> 4, c = col & 15;
    gu[ct] = u + (size_t)(b * kH + h) * kL + c * 64 + k8 * 8;
  }

  // ---- Phase A: w = V @ u
  f32x4 acc[4][2] = {};
#pragma unroll
  for (int ks = 0; ks < 2; ks++) {
    f16x8 af[4], ufl[2];
#pragma unroll
    for (int rt = 0; rt < 4; rt++)
      af[rt] = *(const f16x8*)(aa + (size_t)((ks * 4 + rt) * 64 + lane) * 8);
#pragma unroll
    for (int ct = 0; ct < 2; ct++)
      ufl[ct] = *(const f16x8*)(gu[ct] + ks * 32);
#pragma unroll
    for (int rt = 0; rt < 4; rt++)
#pragma unroll
      for (int ct = 0; ct < 2; ct++)
        acc[rt][ct] =
            __builtin_amdgcn_mfma_f32_16x16x32_f16(af[rt], ufl[ct], acc[rt][ct], 0, 0, 0);
  }

  // ---- Phase B: prefix scan across chunks (cl lanes), per rt — DPP scan
  int lhb = (layer * kH + h) * 32;
#pragma unroll
  for (int rt = 0; rt < 4; rt++) {
    int n0 = rt * 8 + k8 * 2;
    float t0r = rT[(lhb + n0) * 2], t0i = rT[(lhb + n0) * 2 + 1];
    float t1r = rT[(lhb + n0 + 1) * 2], t1i = rT[(lhb + n0 + 1) * 2 + 1];
    scan_level<1, 2>(acc[rt], t0r, t0i, t1r, t1i);
    csq(t0r, t0i); csq(t1r, t1i);
    scan_level<2, 2>(acc[rt], t0r, t0i, t1r, t1i);
    csq(t0r, t0i); csq(t1r, t1i);
    scan_level<4, 2>(acc[rt], t0r, t0i, t1r, t1i);
    csq(t0r, t0i); csq(t1r, t1i);
    scan_level<8, 2>(acc[rt], t0r, t0i, t1r, t1i);
  }

  // ---- Phase C: exclusive shift (DPP row_shr:1, zero-fill), write S to LDS
#pragma unroll
  for (int rt = 0; rt < 4; rt++)
#pragma unroll
    for (int ct = 0; ct < 2; ct++) {
      f16x4 v;
#pragma unroll
      for (int reg = 0; reg < 4; reg++) {
        v[reg] = (f16)dpp_shr0<1>(acc[rt][ct][reg]);
      }
      *(f16x4*)&Sl[w][ct][cl][rt * 16 + k8 * 4] = v;
    }
  // wave-local LDS write->read ordering (each wave touches only Sl[w])
  asm volatile("s_waitcnt lgkmcnt(0)" ::: "memory");

  // ---- Phase D: y = [Ktoep | W2] @ [u; S]
  f32x4 accD[4][2] = {};
#pragma unroll
  for (int ks = 0; ks < 4; ks++) {
    f16x8 af[4], bf[2];
#pragma unroll
    for (int rt = 0; rt < 4; rt++)
      af[rt] = *(const f16x8*)(ac + (size_t)((ks * 4 + rt) * 64 + lane) * 8);
#pragma unroll
    for (int ct = 0; ct < 2; ct++) {
      if (ks < 2)
        bf[ct] = *(const f16x8*)(gu[ct] + ks * 32);
      else
        bf[ct] = *(const f16x8*)&Sl[w][ct][cl][(ks - 2) * 32 + k8 * 8];
    }
#pragma unroll
    for (int rt = 0; rt < 4; rt++)
#pragma unroll
      for (int ct = 0; ct < 2; ct++)
        accD[rt][ct] =
            __builtin_amdgcn_mfma_f32_16x16x32_f16(af[rt], bf[ct], accD[rt][ct], 0, 0, 0);
  }

  // ---- epilogue 1: GELU -> LDS y-tile (j = wave id contiguous)
#pragma unroll
  for (int ct = 0; ct < 2; ct++) {
    int colIdx = ct * 16 + cl;
#pragma unroll
    for (int rt = 0; rt < 4; rt++) {
#pragma unroll
      for (int reg = 0; reg < 4; reg++) {
        Yt[colIdx][rt * 16 + k8 * 4 + reg][w] = (f16)gelu_tanh(accD[rt][ct][reg]);
      }
    }
  }
  __syncthreads();

  // ---- epilogue 2: gather 8-h words, store ytF (256B contiguous / 16 thr)
  {
    int colIdx = tid >> 4, pos = tid & 15;
    int col = col0 + colIdx;
    int b = col >> 4, c = col & 15;
    int kc = blockIdx.y >> 2, hi = blockIdx.y & 3;
#pragma unroll
    for (int rt = 0; rt < 4; rt++) {
      f16x8 word = *(const f16x8*)&Yt[colIdx][rt * 16 + pos][0];
      size_t off = (((size_t)(b * 64 + c * 4 + rt) * 16) + kc) * 512 +
                   (size_t)(hi * 16 + pos) * 8;
      *(f16x8*)(ytF + off) = word;
    }
  }
}

// ---------------------------------------------------------------------------
// K4: GLU GEMM v8 (R6-measured: 51.2us, VGPR 92, 4-wave blocks, B-prefetch).
// R8's 1-wave re-grid regressed to 64us at identical VGPR/occupancy: per-CU
// workgroup-slot limit + loss of correlated woF L2 accesses. Keep >=4 waves.
// History: R3 A+B prefetch -> 132 VGPR cliff (87us). R5 launch_bounds(256,4)
// -> clamp to 64 VGPR + scratch spill (88us). NEVER add min-waves here.
// ---------------------------------------------------------------------------
__global__ __launch_bounds__(256) void glu_mfma_kernel(
    const f16* __restrict__ ytF,  // fragment-ordered y^T
    const f16* __restrict__ woF,  // fragment-ordered Wo, this layer
    const float* __restrict__ bo, // (2H,)
    f16* __restrict__ uout) {     // (B, H, L)
  int tid = threadIdx.x;
  int lane = tid & 63, w = tid >> 6;
  int wm = w >> 1, wn = w & 1;
  int b = blockIdx.z, h0 = blockIdx.y * 64, l0 = blockIdx.x * 128;

  // B fragment base: l-tile (l0>>4)+wn*4+nt, k-chunk kc
  const f16* gB[4];
#pragma unroll
  for (int nt = 0; nt < 4; ++nt)
    gB[nt] = ytF + ((size_t)(b * 64 + (l0 >> 4) + wn * 4 + nt) * 16) * 512 +
             (size_t)lane * 8;

  // A fragment pointers: 4 m-subtiles for this wave (2 per GLU half)
  const f16* gA[4];
#pragma unroll
  for (int i = 0; i < 4; ++i) {
    int mt = (i < 2) ? ((h0 >> 4) + wm * 2 + i) : (32 + (h0 >> 4) + wm * 2 + (i - 2));
    gA[i] = woF + ((size_t)mt * 16 * 64 + lane) * 8;
  }

  f32x4 acc[4][4] = {};
  f16x8 bv[2][4];

#pragma unroll
  for (int nt = 0; nt < 4; ++nt) bv[0][nt] = *(const f16x8*)(gB[nt]);

#pragma unroll
  for (int kc = 0; kc < 16; ++kc) {
    int cur = kc & 1, nxt = cur ^ 1;  // static under full unroll
    if (kc < 15) {
#pragma unroll
      for (int nt = 0; nt < 4; ++nt)
        bv[nxt][nt] = *(const f16x8*)(gB[nt] + (size_t)(kc + 1) * 512);
    }
    f16x8 av[4];
#pragma unroll
    for (int i = 0; i < 4; ++i)
      av[i] = *(const f16x8*)(gA[i] + (size_t)kc * 512);
#pragma unroll
    for (int i = 0; i < 4; ++i)
#pragma unroll
      for (int nt = 0; nt < 4; ++nt)
        acc[i][nt] =
            __builtin_amdgcn_mfma_f32_16x16x32_f16(av[i], bv[cur][nt], acc[i][nt], 0, 0, 0);
  }

  int col = lane & 15, q = lane >> 4;
  f16* ub = uout + (size_t)b * kH * kL;
#pragma unroll
  for (int i = 0; i < 2; ++i) {
#pragma unroll
    for (int reg = 0; reg < 4; ++reg) {
      int h = h0 + wm * 32 + i * 16 + q * 4 + reg;
      float b1 = bo[h], b2 = bo[h + kH];
#pragma unroll
      for (int nt = 0; nt < 4; ++nt) {
        float z1 = acc[i][nt][reg] + b1;
        float z2 = acc[i + 2][nt][reg] + b2;
        float sg = 1.f / (1.f + __expf(-z2));
        ub[(size_t)h * kL + l0 + wn * 64 + nt * 16 + col] = (f16)(z1 * sg);
      }
    }
  }
}

// ---------------------------------------------------------------------------
// K5: final projection via MFMA f16 (unchanged).
// ---------------------------------------------------------------------------
__global__ __launch_bounds__(256) void final_mfma_kernel(
    const f16* __restrict__ x, const f16* __restrict__ wout,
    const float* __restrict__ bout, float* __restrict__ outp) {
  __shared__ __align__(16) f16 At[16][64][8];
  __shared__ __align__(16) f16 Bt[16][64][8];
  int tid = threadIdx.x;
  int lane = tid & 63, w = tid >> 6;
  int wm = w >> 1, wn = w & 1;
  int lr = lane & 15, lc = lane >> 4;
  int b = blockIdx.z, p0 = blockIdx.y * 128, h0 = blockIdx.x * 128;
  const f16* xb = x + (size_t)b * kH * kL;

  f32x4 acc[4][4] = {};

  const f16* gA[4];
  const f16* gB[4];
#pragma unroll
  for (int i = 0; i < 4; ++i) {
    int st = w * 4 + i, mt = st >> 1, ks = st & 1;
    int prow = p0 + mt * 16 + lr;
    if (prow > kP - 1) prow = kP - 1;
    gA[i] = wout + (size_t)prow * kL + ks * 32 + lc * 8;
    int hrow = h0 + mt * 16 + lr;
    gB[i] = xb + (size_t)hrow * kL + ks * 32 + lc * 8;
  }

  for (int k0 = 0; k0 < kL; k0 += 64) {
#pragma unroll
    for (int i = 0; i < 4; ++i) {
      int st = w * 4 + i;
      llds16(gA[i] + k0, &At[st][0][0]);
      llds16(gB[i] + k0, &Bt[st][0][0]);
    }
    __syncthreads();
#pragma unroll
    for (int ks = 0; ks < 2; ++ks) {
      f16x8 av[4], bv[4];
#pragma unroll
      for (int i = 0; i < 4; ++i)
        av[i] = *(const f16x8*)At[(wm * 4 + i) * 2 + ks][lane];
#pragma unroll
      for (int nt = 0; nt < 4; ++nt)
        bv[nt] = *(const f16x8*)Bt[(wn * 4 + nt) * 2 + ks][lane];
#pragma unroll
      for (int i = 0; i < 4; ++i)
#pragma unroll
        for (int nt = 0; nt < 4; ++nt)
          acc[i][nt] =
              __builtin_amdgcn_mfma_f32_16x16x32_f16(av[i], bv[nt], acc[i][nt], 0, 0, 0);
    }
    __syncthreads();
  }

  int col = lane & 15, q = lane >> 4;
  float* ob = outp + (size_t)b * kP * kH;
#pragma unroll
  for (int i = 0; i < 4; ++i) {
#pragma unroll
    for (int reg = 0; reg < 4; ++reg) {
      int p = p0 + wm * 64 + i * 16 + q * 4 + reg;
      if (p < kP) {
        float bv2 = bout[p];
#pragma unroll
        for (int nt = 0; nt < 4; ++nt)
          ob[(size_t)p * kH + h0 + wn * 64 + nt * 16 + col] = acc[i][nt][reg] + bv2;
      }
    }
  }
}

}  // namespace

extern "C" void kernel_launch(void* const* d_in, const int* in_sizes, int n_in,
                              void* d_out, int out_size, void* d_ws, size_t ws_size,
                              hipStream_t stream) {
  const float* x_enc  = (const float*)d_in[0];
  const float* log_dt = (const float*)d_in[4];
  const float* A_re   = (const float*)d_in[5];
  const float* A_im   = (const float*)d_in[6];
  const float* C_re   = (const float*)d_in[7];
  const float* C_im   = (const float*)d_in[8];
  const float* Dskip  = (const float*)d_in[9];
  const float* Wo     = (const float*)d_in[10];
  const float* bo     = (const float*)d_in[11];
  const float* W_out  = (const float*)d_in[12];
  const float* b_out  = (const float*)d_in[13];
  float* out = (float*)d_out;

  char* wsb = (char*)d_ws;
  f16* u16    = (f16*)(wsb);                   // 32 MB: u (B,H,L)
  f16* ytF    = (f16*)(wsb + 67108864);        // 32 MB: fragment-ordered y^T
  f16* woF    = (f16*)(wsb + 100663296);       // 3 MB fragment-ordered Wo
  f16* wout16 = (f16*)(wsb + 103809024);       // 672 KB
  f16* afc    = (f16*)(wsb + 104497152);       // 24 MB  [lh][16][64][8]
  f16* afa    = (f16*)(wsb + 129662976);       // 12 MB  [lh][8][64][8]
  float* rT   = (float*)(wsb + 142245888);     // 384 KB [lh][32][2]

  const int nwp = kP * kL;
  f32_to_f16_kernel<<<(nwp + 255) / 256, 256, 0, stream>>>(W_out, wout16, nwp);
  wo_frag_kernel<<<dim3(64, kNL), 256, 0, stream>>>(Wo, woF);

  prep_kernel<<<kNL * kH, 64, 0, stream>>>(log_dt, A_re, A_im, C_re, C_im, Dskip,
                                           afc, afa, rT);

  transpose_kernel<<<dim3(kL / 32, kH / 32, kB), dim3(32, 8), 0, stream>>>(x_enc, u16);

  for (int layer = 0; layer < kNL; layer++) {
    chunk_wyt_kernel<<<dim3(16, kH / 8), 512, 0, stream>>>(u16, afa, afc, rT, ytF, layer);
    glu_mfma_kernel<<<dim3(kL / 128, kH / 64, kB), 256, 0, stream>>>(
        ytF, woF + (size_t)layer * 64 * 8192, bo + (size_t)layer * 2 * kH, u16);
  }

  final_mfma_kernel<<<dim3(kH / 128, 3, kB), 256, 0, stream>>>(u16, wout16, b_out, out);
}

// Round 12
// 435.692 us; speedup vs baseline: 1.1067x; 1.0098x over previous
//
#include <hip/hip_runtime.h>
#include <math.h>

typedef _Float16 f16;
typedef f16 f16x4 __attribute__((ext_vector_type(4)));
typedef f16 f16x8 __attribute__((ext_vector_type(8)));
typedef float f32x4 __attribute__((ext_vector_type(4)));

namespace {

constexpr int kB  = 32;
constexpr int kL  = 1024;
constexpr int kH  = 512;
constexpr int kP  = 336;
constexpr int kNL = 3;
constexpr int kNS = 32;
constexpr int kM  = 16;   // chunks per row (L/64)

// async global->LDS, 16B per lane. LDS dest is wave-uniform base + lane*16.
__device__ __forceinline__ void llds16(const void* g, void* s) {
  __builtin_amdgcn_global_load_lds((const __attribute__((address_space(1))) void*)g,
                                   (__attribute__((address_space(3))) void*)s, 16, 0, 0);
}

__device__ __forceinline__ float gelu_tanh(float y0) {
  float x3 = y0 * y0 * y0;
  float a = 0.7978845608028654f * fmaf(0.044715f, x3, y0);
  float aa = fminf(a, 15.f);
  float ex = __expf(2.f * aa);
  float th = 1.f - 2.f / (ex + 1.f);
  return 0.5f * y0 * (1.f + th);
}

// DPP row_shr:DIST within 16-lane rows, zero-fill for lanes (lane&15) < DIST.
template <int DIST>
__device__ __forceinline__ float dpp_shr0(float x) {
  return __builtin_bit_cast(float,
      __builtin_amdgcn_update_dpp(0, __builtin_bit_cast(int, x),
                                  0x110 | DIST, 0xF, 0xF, true));
}

__device__ __forceinline__ void csq(float& r, float& i) {
  float nr = r * r - i * i;
  i = 2.f * r * i;
  r = nr;
}

template <int DIST, int NCT>
__device__ __forceinline__ void scan_level(f32x4 (&a)[NCT], float t0r, float t0i,
                                           float t1r, float t1i) {
#pragma unroll
  for (int ct = 0; ct < NCT; ct++) {
    float r0 = dpp_shr0<DIST>(a[ct][0]);
    float i0 = dpp_shr0<DIST>(a[ct][1]);
    float r1 = dpp_shr0<DIST>(a[ct][2]);
    float i1 = dpp_shr0<DIST>(a[ct][3]);
    a[ct][0] = fmaf(t0r, r0, fmaf(-t0i, i0, a[ct][0]));
    a[ct][1] = fmaf(t0r, i0, fmaf(t0i, r0, a[ct][1]));
    a[ct][2] = fmaf(t1r, r1, fmaf(-t1i, i1, a[ct][2]));
    a[ct][3] = fmaf(t1r, i1, fmaf(t1i, r1, a[ct][3]));
  }
}

// ---------------------------------------------------------------------------
// K_pre: per (layer,h) build chunked-scan operands.
// ---------------------------------------------------------------------------
__global__ __launch_bounds__(64) void prep_kernel(
    const float* __restrict__ log_dt, const float* __restrict__ A_re,
    const float* __restrict__ A_im, const float* __restrict__ C_re,
    const float* __restrict__ C_im, const float* __restrict__ Dskip,
    f16* __restrict__ Afrag_c, f16* __restrict__ Afrag_a,
    float* __restrict__ rT) {
  int lh = blockIdx.x;   // layer*H + h
  int tid = threadIdx.x; // 0..63
  __shared__ float pr[32][65], pi[32][65];
  __shared__ float cre_s[32], cim_s[32];
  __shared__ float kt[64];

  float dt = expf(log_dt[lh]);
  if (tid < 32) {
    int n = tid;
    int idx = lh * 32 + n;
    float ar = A_re[idx], ai = A_im[idx];
    float dr = dt * ar, di = dt * ai;
    float er = expf(dr), cd = cosf(di), sd = sinf(di);
    float rr = er * cd, ri = er * sd;
    float sh = sinf(0.5f * di);
    float mr = expm1f(dr) * cd - 2.f * sh * sh;
    float mi = ri;
    float inv = 1.f / (ar * ar + ai * ai);
    float qr = (mr * ar + mi * ai) * inv;
    float qi = (mi * ar - mr * ai) * inv;
    float cre = C_re[idx], cim = C_im[idx];
    cre_s[n] = 2.f * (cre * qr - cim * qi);
    cim_s[n] = 2.f * (cre * qi + cim * qr);
    float xr = 1.f, xi = 0.f;
    for (int k = 0; k < 65; k++) {
      pr[n][k] = xr;
      pi[n][k] = xi;
      float nxr = xr * rr - xi * ri;
      float nxi = xr * ri + xi * rr;
      xr = nxr;
      xi = nxi;
    }
    rT[idx * 2] = pr[n][64];
    rT[idx * 2 + 1] = pi[n][64];
  }
  __syncthreads();
  {
    int d = tid;
    float s = 0.f;
    for (int n = 0; n < 32; n++) s += cre_s[n] * pr[n][d] - cim_s[n] * pi[n][d];
    if (d == 0) s += Dskip[lh];
    kt[d] = s;
  }
  __syncthreads();
  // A_c fragments: [K_toep | W2]
  f16* ac = Afrag_c + (size_t)lh * 8192;
#pragma unroll
  for (int it = 0; it < 16; it++) {
    int ks = it >> 2, rt = it & 3;
    int t = rt * 16 + (tid & 15);
    int kbase = ks * 32 + (tid >> 4) * 8;
    f16x8 v;
#pragma unroll
    for (int j = 0; j < 8; j++) {
      int k = kbase + j;
      float val;
      if (k < 64) {
        val = (t >= k) ? kt[t - k] : 0.f;
      } else {
        int s2 = k - 64;
        int n = s2 >> 1;
        float prr = pr[n][t + 1], pii = pi[n][t + 1];
        val = ((s2 & 1) == 0) ? (cre_s[n] * prr - cim_s[n] * pii)
                              : -(cre_s[n] * pii + cim_s[n] * prr);
      }
      v[j] = (f16)val;
    }
    *(f16x8*)(ac + (size_t)(it * 64 + tid) * 8) = v;
  }
  // A_a fragments (V)
  f16* aa = Afrag_a + (size_t)lh * 4096;
#pragma unroll
  for (int it = 0; it < 8; it++) {
    int ks = it >> 2, rt = it & 3;
    int s2 = rt * 16 + (tid & 15);
    int n = s2 >> 1;
    int kbase = ks * 32 + (tid >> 4) * 8;
    f16x8 v;
#pragma unroll
    for (int j = 0; j < 8; j++) {
      int t = kbase + j;
      v[j] = (f16)(((s2 & 1) == 0) ? pr[n][63 - t] : pi[n][63 - t]);
    }
    *(f16x8*)(aa + (size_t)(it * 64 + tid) * 8) = v;
  }
}

// ---------------------------------------------------------------------------
// K1: fp32 -> fp16 convert (weights)
// ---------------------------------------------------------------------------
__global__ void f32_to_f16_kernel(const float* __restrict__ s, f16* __restrict__ d,
                                  int n) {
  int i = blockIdx.x * 256 + threadIdx.x;
  if (i < n) d[i] = (f16)s[i];
}

// ---------------------------------------------------------------------------
// K1b: Wo fp32 -> MFMA-A-fragment-ordered fp16.
// woF[layer][mt(64)][ks(16)][lane(64)][8] = Wo[mt*16+(lane&15)][ks*32+(lane>>4)*8+j]
// ---------------------------------------------------------------------------
__global__ __launch_bounds__(256) void wo_frag_kernel(const float* __restrict__ Wo,
                                                      f16* __restrict__ woF) {
  int layer = blockIdx.y, mt = blockIdx.x;
  int t = threadIdx.x;
  int lane = t & 63;
  const float* w = Wo + (size_t)layer * 2 * kH * kH;
  f16* dst = woF + ((size_t)layer * 64 + mt) * 8192;
  int row = mt * 16 + (lane & 15);
  int cbase = (lane >> 4) * 8;
#pragma unroll
  for (int it = 0; it < 4; it++) {
    int ks = it * 4 + (t >> 6);
    f16x8 v;
#pragma unroll
    for (int j = 0; j < 8; j++) v[j] = (f16)w[(size_t)row * kH + ks * 32 + cbase + j];
    *(f16x8*)(dst + (size_t)(ks * 64 + lane) * 8) = v;
  }
}

// ---------------------------------------------------------------------------
// K2: (B, L, E) fp32 -> (B, E, L) fp16 transpose (input)
// ---------------------------------------------------------------------------
__global__ __launch_bounds__(256) void transpose_kernel(const float* __restrict__ x,
                                                        f16* __restrict__ u) {
  __shared__ float tile[32][33];
  int b = blockIdx.z;
  int l0 = blockIdx.x * 32, e0 = blockIdx.y * 32;
  int tx = threadIdx.x, ty = threadIdx.y;  // (32, 8)
#pragma unroll
  for (int k = 0; k < 4; k++)
    tile[ty + 8 * k][tx] = x[((size_t)b * kL + (size_t)(l0 + ty + 8 * k)) * kH + e0 + tx];
  __syncthreads();
#pragma unroll
  for (int k = 0; k < 4; k++)
    u[((size_t)b * kH + (size_t)(e0 + ty + 8 * k)) * kL + l0 + tx] =
        (f16)tile[tx][ty + 8 * k];
}

// ---------------------------------------------------------------------------
// K_wyt v2 (R21): fused chunk-scan + fragment-reorder (from R20) with two
// latency tweaks for the scan-serial section:
//  (a) uf carried across the scan (R2 pattern) — Phase D no longer re-loads
//      u from global (+16 VGPR, saves 4KB L2 reads + D-phase load latency);
//  (b) Phase D's ks=0 A-fragment set prefetched BEFORE the DPP scan — its
//      ~200cyc latency hides under the serial VALU chain (+16 VGPR).
// Budget ~122 VGPR, same <=128 tier as R20.
// ---------------------------------------------------------------------------
__global__ __launch_bounds__(512) void chunk_wyt_kernel(
    const f16* __restrict__ u, const f16* __restrict__ Afrag_a,
    const f16* __restrict__ Afrag_c, const float* __restrict__ rT,
    f16* __restrict__ ytF, int layer) {
  __shared__ __align__(16) f16 Sl[8][2][16][72];  // per-wave scan buffer
  __shared__ __align__(16) f16 Yt[32][65][8];     // [colIdx][t (64, pad 65)][j]
  int tid = threadIdx.x;
  int w = tid >> 6, lane = tid & 63;
  int h = blockIdx.y * 8 + w;  // aligned octet: kc, hi uniform over block
  int col0 = blockIdx.x * 32;
  const f16* aa = Afrag_a + (size_t)(layer * kH + h) * 4096;
  const f16* ac = Afrag_c + (size_t)(layer * kH + h) * 8192;
  int k8 = lane >> 4, cl = lane & 15;

  // u fragment addresses (16B per lane)
  const f16* gu[2];
#pragma unroll
  for (int ct = 0; ct < 2; ct++) {
    int col = col0 + ct * 16 + cl;
    int b = col >> 4, c = col & 15;
    gu[ct] = u + (size_t)(b * kH + h) * kL + c * 64 + k8 * 8;
  }

  // ---- Phase A: w = V @ u (uf CARRIED through the scan for Phase D)
  f16x8 uf[2][2];
  f32x4 acc[4][2] = {};
#pragma unroll
  for (int ks = 0; ks < 2; ks++) {
    f16x8 af[4];
#pragma unroll
    for (int rt = 0; rt < 4; rt++)
      af[rt] = *(const f16x8*)(aa + (size_t)((ks * 4 + rt) * 64 + lane) * 8);
#pragma unroll
    for (int ct = 0; ct < 2; ct++)
      uf[ct][ks] = *(const f16x8*)(gu[ct] + ks * 32);
#pragma unroll
    for (int rt = 0; rt < 4; rt++)
#pragma unroll
      for (int ct = 0; ct < 2; ct++)
        acc[rt][ct] =
            __builtin_amdgcn_mfma_f32_16x16x32_f16(af[rt], uf[ct][ks], acc[rt][ct], 0, 0, 0);
  }

  // prefetch Phase D's ks=0 A-fragments — latency hides under the scan
  f16x8 afd0[4];
#pragma unroll
  for (int rt = 0; rt < 4; rt++)
    afd0[rt] = *(const f16x8*)(ac + (size_t)(rt * 64 + lane) * 8);

  // ---- Phase B: prefix scan across chunks (cl lanes), per rt — DPP scan
  int lhb = (layer * kH + h) * 32;
#pragma unroll
  for (int rt = 0; rt < 4; rt++) {
    int n0 = rt * 8 + k8 * 2;
    float t0r = rT[(lhb + n0) * 2], t0i = rT[(lhb + n0) * 2 + 1];
    float t1r = rT[(lhb + n0 + 1) * 2], t1i = rT[(lhb + n0 + 1) * 2 + 1];
    scan_level<1, 2>(acc[rt], t0r, t0i, t1r, t1i);
    csq(t0r, t0i); csq(t1r, t1i);
    scan_level<2, 2>(acc[rt], t0r, t0i, t1r, t1i);
    csq(t0r, t0i); csq(t1r, t1i);
    scan_level<4, 2>(acc[rt], t0r, t0i, t1r, t1i);
    csq(t0r, t0i); csq(t1r, t1i);
    scan_level<8, 2>(acc[rt], t0r, t0i, t1r, t1i);
  }

  // ---- Phase C: exclusive shift (DPP row_shr:1, zero-fill), write S to LDS
#pragma unroll
  for (int rt = 0; rt < 4; rt++)
#pragma unroll
    for (int ct = 0; ct < 2; ct++) {
      f16x4 v;
#pragma unroll
      for (int reg = 0; reg < 4; reg++) {
        v[reg] = (f16)dpp_shr0<1>(acc[rt][ct][reg]);
      }
      *(f16x4*)&Sl[w][ct][cl][rt * 16 + k8 * 4] = v;
    }
  // wave-local LDS write->read ordering (each wave touches only Sl[w])
  asm volatile("s_waitcnt lgkmcnt(0)" ::: "memory");

  // ---- Phase D: y = [Ktoep | W2] @ [u; S]
  f32x4 accD[4][2] = {};
#pragma unroll
  for (int ks = 0; ks < 4; ks++) {
    f16x8 af[4], bf[2];
#pragma unroll
    for (int rt = 0; rt < 4; rt++) {
      if (ks == 0)
        af[rt] = afd0[rt];
      else
        af[rt] = *(const f16x8*)(ac + (size_t)((ks * 4 + rt) * 64 + lane) * 8);
    }
#pragma unroll
    for (int ct = 0; ct < 2; ct++) {
      if (ks < 2)
        bf[ct] = uf[ct][ks];
      else
        bf[ct] = *(const f16x8*)&Sl[w][ct][cl][(ks - 2) * 32 + k8 * 8];
    }
#pragma unroll
    for (int rt = 0; rt < 4; rt++)
#pragma unroll
      for (int ct = 0; ct < 2; ct++)
        accD[rt][ct] =
            __builtin_amdgcn_mfma_f32_16x16x32_f16(af[rt], bf[ct], accD[rt][ct], 0, 0, 0);
  }

  // ---- epilogue 1: GELU -> LDS y-tile (j = wave id contiguous)
#pragma unroll
  for (int ct = 0; ct < 2; ct++) {
    int colIdx = ct * 16 + cl;
#pragma unroll
    for (int rt = 0; rt < 4; rt++) {
#pragma unroll
      for (int reg = 0; reg < 4; reg++) {
        Yt[colIdx][rt * 16 + k8 * 4 + reg][w] = (f16)gelu_tanh(accD[rt][ct][reg]);
      }
    }
  }
  __syncthreads();

  // ---- epilogue 2: gather 8-h words, store ytF (256B contiguous / 16 thr)
  {
    int colIdx = tid >> 4, pos = tid & 15;
    int col = col0 + colIdx;
    int b = col >> 4, c = col & 15;
    int kc = blockIdx.y >> 2, hi = blockIdx.y & 3;
#pragma unroll
    for (int rt = 0; rt < 4; rt++) {
      f16x8 word = *(const f16x8*)&Yt[colIdx][rt * 16 + pos][0];
      size_t off = (((size_t)(b * 64 + c * 4 + rt) * 16) + kc) * 512 +
                   (size_t)(hi * 16 + pos) * 8;
      *(f16x8*)(ytF + off) = word;
    }
  }
}

// ---------------------------------------------------------------------------
// K4: GLU GEMM v10 (R21). v8 body (R6-measured 51.2us, VGPR 92, B-prefetch)
// + XCD-chunk swizzle: grid flattened to 1D 2048 (2048%8==0 -> simple
// bijective m157 form). Each XCD gets a CONTIGUOUS chunk of 256 original
// ids = 32 full (h0,b) A-groups; per-XCD working set ~ 4 batches x 1MB ytF
// + 1MB woF ~ L2 size -> both operands near-resident per XCD.
// History: R3 A+B prefetch -> 132 VGPR cliff (87us). R5 launch_bounds(256,4)
// -> 64-VGPR clamp + spill (88us). R8 1-wave blocks -> 64us (wg-slot limit).
// ---------------------------------------------------------------------------
__global__ __launch_bounds__(256) void glu_mfma_kernel(
    const f16* __restrict__ ytF,  // fragment-ordered y^T
    const f16* __restrict__ woF,  // fragment-ordered Wo, this layer
    const float* __restrict__ bo, // (2H,)
    f16* __restrict__ uout) {     // (B, H, L)
  int tid = threadIdx.x;
  int lane = tid & 63, w = tid >> 6;
  int wm = w >> 1, wn = w & 1;
  // XCD-chunk swizzle: xcd = wg&7 processes contiguous orig ids
  int wg = blockIdx.x;
  int orig = ((wg & 7) << 8) + (wg >> 3);  // 2048/8 = 256 per XCD
  int l0 = (orig & 7) * 128;
  int h0 = ((orig >> 3) & 7) * 64;
  int b = orig >> 6;

  // B fragment base: l-tile (l0>>4)+wn*4+nt, k-chunk kc
  const f16* gB[4];
#pragma unroll
  for (int nt = 0; nt < 4; ++nt)
    gB[nt] = ytF + ((size_t)(b * 64 + (l0 >> 4) + wn * 4 + nt) * 16) * 512 +
             (size_t)lane * 8;

  // A fragment pointers: 4 m-subtiles for this wave (2 per GLU half)
  const f16* gA[4];
#pragma unroll
  for (int i = 0; i < 4; ++i) {
    int mt = (i < 2) ? ((h0 >> 4) + wm * 2 + i) : (32 + (h0 >> 4) + wm * 2 + (i - 2));
    gA[i] = woF + ((size_t)mt * 16 * 64 + lane) * 8;
  }

  f32x4 acc[4][4] = {};
  f16x8 bv[2][4];

#pragma unroll
  for (int nt = 0; nt < 4; ++nt) bv[0][nt] = *(const f16x8*)(gB[nt]);

#pragma unroll
  for (int kc = 0; kc < 16; ++kc) {
    int cur = kc & 1, nxt = cur ^ 1;  // static under full unroll
    if (kc < 15) {
#pragma unroll
      for (int nt = 0; nt < 4; ++nt)
        bv[nxt][nt] = *(const f16x8*)(gB[nt] + (size_t)(kc + 1) * 512);
    }
    f16x8 av[4];
#pragma unroll
    for (int i = 0; i < 4; ++i)
      av[i] = *(const f16x8*)(gA[i] + (size_t)kc * 512);
#pragma unroll
    for (int i = 0; i < 4; ++i)
#pragma unroll
      for (int nt = 0; nt < 4; ++nt)
        acc[i][nt] =
            __builtin_amdgcn_mfma_f32_16x16x32_f16(av[i], bv[cur][nt], acc[i][nt], 0, 0, 0);
  }

  int col = lane & 15, q = lane >> 4;
  f16* ub = uout + (size_t)b * kH * kL;
#pragma unroll
  for (int i = 0; i < 2; ++i) {
#pragma unroll
    for (int reg = 0; reg < 4; ++reg) {
      int h = h0 + wm * 32 + i * 16 + q * 4 + reg;
      float b1 = bo[h], b2 = bo[h + kH];
#pragma unroll
      for (int nt = 0; nt < 4; ++nt) {
        float z1 = acc[i][nt][reg] + b1;
        float z2 = acc[i + 2][nt][reg] + b2;
        float sg = 1.f / (1.f + __expf(-z2));
        ub[(size_t)h * kL + l0 + wn * 64 + nt * 16 + col] = (f16)(z1 * sg);
      }
    }
  }
}

// ---------------------------------------------------------------------------
// K5: final projection via MFMA f16 (unchanged).
// ---------------------------------------------------------------------------
__global__ __launch_bounds__(256) void final_mfma_kernel(
    const f16* __restrict__ x, const f16* __restrict__ wout,
    const float* __restrict__ bout, float* __restrict__ outp) {
  __shared__ __align__(16) f16 At[16][64][8];
  __shared__ __align__(16) f16 Bt[16][64][8];
  int tid = threadIdx.x;
  int lane = tid & 63, w = tid >> 6;
  int wm = w >> 1, wn = w & 1;
  int lr = lane & 15, lc = lane >> 4;
  int b = blockIdx.z, p0 = blockIdx.y * 128, h0 = blockIdx.x * 128;
  const f16* xb = x + (size_t)b * kH * kL;

  f32x4 acc[4][4] = {};

  const f16* gA[4];
  const f16* gB[4];
#pragma unroll
  for (int i = 0; i < 4; ++i) {
    int st = w * 4 + i, mt = st >> 1, ks = st & 1;
    int prow = p0 + mt * 16 + lr;
    if (prow > kP - 1) prow = kP - 1;
    gA[i] = wout + (size_t)prow * kL + ks * 32 + lc * 8;
    int hrow = h0 + mt * 16 + lr;
    gB[i] = xb + (size_t)hrow * kL + ks * 32 + lc * 8;
  }

  for (int k0 = 0; k0 < kL; k0 += 64) {
#pragma unroll
    for (int i = 0; i < 4; ++i) {
      int st = w * 4 + i;
      llds16(gA[i] + k0, &At[st][0][0]);
      llds16(gB[i] + k0, &Bt[st][0][0]);
    }
    __syncthreads();
#pragma unroll
    for (int ks = 0; ks < 2; ++ks) {
      f16x8 av[4], bv[4];
#pragma unroll
      for (int i = 0; i < 4; ++i)
        av[i] = *(const f16x8*)At[(wm * 4 + i) * 2 + ks][lane];
#pragma unroll
      for (int nt = 0; nt < 4; ++nt)
        bv[nt] = *(const f16x8*)Bt[(wn * 4 + nt) * 2 + ks][lane];
#pragma unroll
      for (int i = 0; i < 4; ++i)
#pragma unroll
        for (int nt = 0; nt < 4; ++nt)
          acc[i][nt] =
              __builtin_amdgcn_mfma_f32_16x16x32_f16(av[i], bv[nt], acc[i][nt], 0, 0, 0);
    }
    __syncthreads();
  }

  int col = lane & 15, q = lane >> 4;
  float* ob = outp + (size_t)b * kP * kH;
#pragma unroll
  for (int i = 0; i < 4; ++i) {
#pragma unroll
    for (int reg = 0; reg < 4; ++reg) {
      int p = p0 + wm * 64 + i * 16 + q * 4 + reg;
      if (p < kP) {
        float bv2 = bout[p];
#pragma unroll
        for (int nt = 0; nt < 4; ++nt)
          ob[(size_t)p * kH + h0 + wn * 64 + nt * 16 + col] = acc[i][nt][reg] + bv2;
      }
    }
  }
}

}  // namespace

extern "C" void kernel_launch(void* const* d_in, const int* in_sizes, int n_in,
                              void* d_out, int out_size, void* d_ws, size_t ws_size,
                              hipStream_t stream) {
  const float* x_enc  = (const float*)d_in[0];
  const float* log_dt = (const float*)d_in[4];
  const float* A_re   = (const float*)d_in[5];
  const float* A_im   = (const float*)d_in[6];
  const float* C_re   = (const float*)d_in[7];
  const float* C_im   = (const float*)d_in[8];
  const float* Dskip  = (const float*)d_in[9];
  const float* Wo     = (const float*)d_in[10];
  const float* bo     = (const float*)d_in[11];
  const float* W_out  = (const float*)d_in[12];
  const float* b_out  = (const float*)d_in[13];
  float* out = (float*)d_out;

  char* wsb = (char*)d_ws;
  f16* u16    = (f16*)(wsb);                   // 32 MB: u (B,H,L)
  f16* ytF    = (f16*)(wsb + 67108864);        // 32 MB: fragment-ordered y^T
  f16* woF    = (f16*)(wsb + 100663296);       // 3 MB fragment-ordered Wo
  f16* wout16 = (f16*)(wsb + 103809024);       // 672 KB
  f16* afc    = (f16*)(wsb + 104497152);       // 24 MB  [lh][16][64][8]
  f16* afa    = (f16*)(wsb + 129662976);       // 12 MB  [lh][8][64][8]
  float* rT   = (float*)(wsb + 142245888);     // 384 KB [lh][32][2]

  const int nwp = kP * kL;
  f32_to_f16_kernel<<<(nwp + 255) / 256, 256, 0, stream>>>(W_out, wout16, nwp);
  wo_frag_kernel<<<dim3(64, kNL), 256, 0, stream>>>(Wo, woF);

  prep_kernel<<<kNL * kH, 64, 0, stream>>>(log_dt, A_re, A_im, C_re, C_im, Dskip,
                                           afc, afa, rT);

  transpose_kernel<<<dim3(kL / 32, kH / 32, kB), dim3(32, 8), 0, stream>>>(x_enc, u16);

  for (int layer = 0; layer < kNL; layer++) {
    chunk_wyt_kernel<<<dim3(16, kH / 8), 512, 0, stream>>>(u16, afa, afc, rT, ytF, layer);
    glu_mfma_kernel<<<2048, 256, 0, stream>>>(
        ytF, woF + (size_t)layer * 64 * 8192, bo + (size_t)layer * 2 * kH, u16);
  }

  final_mfma_kernel<<<dim3(kH / 128, 3, kB), 256, 0, stream>>>(u16, wout16, b_out, out);
}